// Round 1
// baseline (844.139 us; speedup 1.0000x reference)
//
#include <hip/hip_runtime.h>
#include <hip/hip_bf16.h>

// Problem constants (from reference)
#define BB 32
#define INP 1024
#define WIDTH 256
#define OUTP 1024
#define NE 8
#define HW 196      // 14*14
#define HH 14
#define EPS 1e-5f

#define S1 (WIDTH * INP)        // 262144 per-expert elems of w1
#define S2 (WIDTH * WIDTH * 9)  // 589824 per-expert elems of w2
#define S3 (OUTP * WIDTH)       // 262144 per-expert elems of w3

// ---------------------------------------------------------------------------
// Spatial mean per (b, c): grid = B*C blocks of 64 threads (one wave).
// ---------------------------------------------------------------------------
__global__ __launch_bounds__(64) void mean_kernel(const float* __restrict__ in,
                                                  float* __restrict__ mean) {
    int blk = blockIdx.x;  // b*C + c
    const float* row = in + (size_t)blk * HW;
    int t = threadIdx.x;
    float s = 0.f;
    for (int p = t; p < HW; p += 64) s += row[p];
#pragma unroll
    for (int off = 32; off > 0; off >>= 1) s += __shfl_down(s, off, 64);
    if (t == 0) mean[blk] = s * (1.0f / (float)HW);
}

// ---------------------------------------------------------------------------
// Routing: rw[b,e] = sigmoid(sum_c mean[b,c]*W[c,e] + bias[e]).
// grid = B blocks of 256 threads.
// ---------------------------------------------------------------------------
__global__ __launch_bounds__(256) void route_kernel(const float* __restrict__ mean,
                                                    const float* __restrict__ W,
                                                    const float* __restrict__ bias,
                                                    float* __restrict__ rw, int C) {
    __shared__ float red[NE * 256];
    int b = blockIdx.x, t = threadIdx.x;
    float part[NE];
#pragma unroll
    for (int e = 0; e < NE; e++) part[e] = 0.f;
    for (int c = t; c < C; c += 256) {
        float m = mean[b * C + c];
#pragma unroll
        for (int e = 0; e < NE; e++) part[e] += m * W[c * NE + e];
    }
#pragma unroll
    for (int e = 0; e < NE; e++) red[e * 256 + t] = part[e];
    __syncthreads();
    for (int st = 128; st > 0; st >>= 1) {
        if (t < st) {
#pragma unroll
            for (int e = 0; e < NE; e++) red[e * 256 + t] += red[e * 256 + t + st];
        }
        __syncthreads();
    }
    if (t < NE) {
        float z = red[t * 256] + bias[t];
        rw[b * NE + t] = 1.0f / (1.0f + expf(-z));
    }
}

// ---------------------------------------------------------------------------
// Combine expert weights: cw[b,s] = sum_e rw[b,e] * w[e,s], stored bf16.
// grid = (S/256, B), 256 threads. Coalesced reads of each expert slice.
// ---------------------------------------------------------------------------
__global__ __launch_bounds__(256) void combine_kernel(const float* __restrict__ w,
                                                      const float* __restrict__ rw,
                                                      __hip_bfloat16* __restrict__ cw,
                                                      int S) {
    int b = blockIdx.y;
    int s = blockIdx.x * 256 + threadIdx.x;
    const float* rwb = rw + b * NE;
    float acc = 0.f;
#pragma unroll
    for (int e = 0; e < NE; e++) acc += rwb[e] * w[(size_t)e * S + s];
    cw[(size_t)b * S + s] = __float2bfloat16(acc);
}

// ---------------------------------------------------------------------------
// 1x1 conv as per-sample GEMM + BN (+ optional residual) + ReLU.
// grid = (B, Cout/32), 256 threads (196 active for compute; all stage).
// out[b, o0+o, p] = relu(bn(sum_k cw[b,o,k] * in[b,k,p]) [+ identity])
// ---------------------------------------------------------------------------
__global__ __launch_bounds__(256) void conv1x1_bn_kernel(
    const float* __restrict__ in, const __hip_bfloat16* __restrict__ cw,
    const float* __restrict__ g, const float* __restrict__ beta,
    const float* __restrict__ mu, const float* __restrict__ var,
    const float* __restrict__ identity, float* __restrict__ out,
    int Cin, int Cout) {
    __shared__ float wl[32][8];
    int b = blockIdx.x;
    int o0 = blockIdx.y * 32;
    int tid = threadIdx.x;
    int p = tid;
    bool act = p < HW;
    float acc[32];
#pragma unroll
    for (int o = 0; o < 32; o++) acc[o] = 0.f;

    const __hip_bfloat16* cwb = cw + ((size_t)b * Cout + o0) * Cin;
    const float* inb = in + (size_t)b * Cin * HW;

    int o_st = tid >> 3, k_st = tid & 7;
    for (int k0 = 0; k0 < Cin; k0 += 8) {
        wl[o_st][k_st] = __bfloat162float(cwb[(size_t)o_st * Cin + k0 + k_st]);
        __syncthreads();
        if (act) {
#pragma unroll
            for (int kk = 0; kk < 8; kk++) {
                float xv = inb[(k0 + kk) * HW + p];
#pragma unroll
                for (int o = 0; o < 32; o++) acc[o] += wl[o][kk] * xv;
            }
        }
        __syncthreads();
    }

    if (act) {
#pragma unroll
        for (int o = 0; o < 32; o++) {
            int oc = o0 + o;
            float inv = rsqrtf(var[oc] + EPS) * g[oc];
            float val = acc[o] * inv + (beta[oc] - mu[oc] * inv);
            if (identity) val += identity[((size_t)b * Cout + oc) * HW + p];
            val = fmaxf(val, 0.f);
            out[((size_t)b * Cout + oc) * HW + p] = val;
        }
    }
}

// ---------------------------------------------------------------------------
// 3x3 conv (pad 1) + BN + ReLU. grid = (B, WIDTH/16), 256 threads.
// For each input channel i: stage the 14x14 plane and the 16x9 weight slice
// in LDS, each active thread (p<196) accumulates 16 outputs.
// ---------------------------------------------------------------------------
__global__ __launch_bounds__(256) void conv3x3_bn_kernel(
    const float* __restrict__ in, const __hip_bfloat16* __restrict__ cw,
    const float* __restrict__ g, const float* __restrict__ beta,
    const float* __restrict__ mu, const float* __restrict__ var,
    float* __restrict__ out) {
    __shared__ float plane[HW];
    __shared__ float wl[16 * 9];
    int b = blockIdx.x;
    int o0 = blockIdx.y * 16;
    int tid = threadIdx.x;
    bool act = tid < HW;
    int y = tid / HH, x = tid % HH;
    float acc[16];
#pragma unroll
    for (int o = 0; o < 16; o++) acc[o] = 0.f;

    const float* inb = in + (size_t)b * WIDTH * HW;
    const __hip_bfloat16* cwb = cw + ((size_t)b * WIDTH + o0) * (WIDTH * 9);

    for (int i = 0; i < WIDTH; i++) {
        if (tid < HW) plane[tid] = inb[i * HW + tid];
        if (tid < 144) {
            int o = tid / 9, t9 = tid % 9;
            wl[tid] = __bfloat162float(cwb[o * (WIDTH * 9) + i * 9 + t9]);
        }
        __syncthreads();
        if (act) {
            float n[9];
#pragma unroll
            for (int dy = 0; dy < 3; dy++) {
#pragma unroll
                for (int dx = 0; dx < 3; dx++) {
                    int yy = y + dy - 1, xx = x + dx - 1;
                    n[dy * 3 + dx] = (yy >= 0 && yy < HH && xx >= 0 && xx < HH)
                                         ? plane[yy * HH + xx]
                                         : 0.f;
                }
            }
#pragma unroll
            for (int o = 0; o < 16; o++) {
                float s = 0.f;
#pragma unroll
                for (int t9 = 0; t9 < 9; t9++) s += wl[o * 9 + t9] * n[t9];
                acc[o] += s;
            }
        }
        __syncthreads();
    }

    if (act) {
#pragma unroll
        for (int o = 0; o < 16; o++) {
            int oc = o0 + o;
            float inv = rsqrtf(var[oc] + EPS) * g[oc];
            float val = acc[o] * inv + (beta[oc] - mu[oc] * inv);
            val = fmaxf(val, 0.f);
            out[((size_t)b * WIDTH + oc) * HW + tid] = val;
        }
    }
}

// ---------------------------------------------------------------------------
extern "C" void kernel_launch(void* const* d_in, const int* in_sizes, int n_in,
                              void* d_out, int out_size, void* d_ws, size_t ws_size,
                              hipStream_t stream) {
    const float* x    = (const float*)d_in[0];
    const float* w1   = (const float*)d_in[1];
    const float* w2   = (const float*)d_in[2];
    const float* w3   = (const float*)d_in[3];
    const float* r1_w = (const float*)d_in[4];
    const float* r1_b = (const float*)d_in[5];
    const float* r2_w = (const float*)d_in[6];
    const float* r2_b = (const float*)d_in[7];
    const float* r3_w = (const float*)d_in[8];
    const float* r3_b = (const float*)d_in[9];
    const float* bn1_g = (const float*)d_in[10];
    const float* bn1_b = (const float*)d_in[11];
    const float* bn1_m = (const float*)d_in[12];
    const float* bn1_v = (const float*)d_in[13];
    const float* bn2_g = (const float*)d_in[14];
    const float* bn2_b = (const float*)d_in[15];
    const float* bn2_m = (const float*)d_in[16];
    const float* bn2_v = (const float*)d_in[17];
    const float* bn3_g = (const float*)d_in[18];
    const float* bn3_b = (const float*)d_in[19];
    const float* bn3_m = (const float*)d_in[20];
    const float* bn3_v = (const float*)d_in[21];
    float* out = (float*)d_out;

    // Workspace layout (total ~84.3 MB)
    char* ws = (char*)d_ws;
    size_t off = 0;
    float* meanbuf = (float*)(ws + off); off += (size_t)BB * INP * 4;       // 128 KB
    float* rw1 = (float*)(ws + off); off += BB * NE * 4;
    float* rw2 = (float*)(ws + off); off += BB * NE * 4;
    float* rw3 = (float*)(ws + off); off += BB * NE * 4;
    off = (off + 255) & ~(size_t)255;
    float* act1 = (float*)(ws + off); off += (size_t)BB * WIDTH * HW * 4;   // 6.4 MB
    float* act2 = (float*)(ws + off); off += (size_t)BB * WIDTH * HW * 4;   // 6.4 MB
    __hip_bfloat16* cw1 = (__hip_bfloat16*)(ws + off); off += (size_t)BB * S1 * 2; // 16.8 MB
    __hip_bfloat16* cw2 = (__hip_bfloat16*)(ws + off); off += (size_t)BB * S2 * 2; // 37.7 MB
    __hip_bfloat16* cw3 = (__hip_bfloat16*)(ws + off); off += (size_t)BB * S3 * 2; // 16.8 MB
    (void)ws_size;

    // Stage 1: route on x, combine w1, 1x1 conv 1024->256 + bn1 + relu
    mean_kernel<<<BB * INP, 64, 0, stream>>>(x, meanbuf);
    route_kernel<<<BB, 256, 0, stream>>>(meanbuf, r1_w, r1_b, rw1, INP);
    combine_kernel<<<dim3(S1 / 256, BB), 256, 0, stream>>>(w1, rw1, cw1, S1);
    conv1x1_bn_kernel<<<dim3(BB, WIDTH / 32), 256, 0, stream>>>(
        x, cw1, bn1_g, bn1_b, bn1_m, bn1_v, nullptr, act1, INP, WIDTH);

    // Stage 2: route on act1, combine w2, 3x3 conv + bn2 + relu
    mean_kernel<<<BB * WIDTH, 64, 0, stream>>>(act1, meanbuf);
    route_kernel<<<BB, 256, 0, stream>>>(meanbuf, r2_w, r2_b, rw2, WIDTH);
    combine_kernel<<<dim3(S2 / 256, BB), 256, 0, stream>>>(w2, rw2, cw2, S2);
    conv3x3_bn_kernel<<<dim3(BB, WIDTH / 16), 256, 0, stream>>>(
        act1, cw2, bn2_g, bn2_b, bn2_m, bn2_v, act2);

    // Stage 3: route on act2, combine w3, 1x1 conv 256->1024 + bn3 + residual + relu
    mean_kernel<<<BB * WIDTH, 64, 0, stream>>>(act2, meanbuf);
    route_kernel<<<BB, 256, 0, stream>>>(meanbuf, r3_w, r3_b, rw3, WIDTH);
    combine_kernel<<<dim3(S3 / 256, BB), 256, 0, stream>>>(w3, rw3, cw3, S3);
    conv1x1_bn_kernel<<<dim3(BB, OUTP / 32), 256, 0, stream>>>(
        act2, cw3, bn3_g, bn3_b, bn3_m, bn3_v, x, out, WIDTH, OUTP);
}

// Round 2
// 484.245 us; speedup vs baseline: 1.7432x; 1.7432x over previous
//
#include <hip/hip_runtime.h>
#include <hip/hip_bf16.h>

// Problem constants
#define BB 32
#define INP 1024
#define WIDTH 256
#define OUTP 1024
#define NE 8
#define HW 196
#define HH 14
#define NP 224      // padded pixel count (14 n-tiles of 16)
#define EPS 1e-5f

#define S1 (WIDTH * INP)        // 262144
#define S2 (WIDTH * WIDTH * 9)  // 589824
#define S3 (OUTP * WIDTH)       // 262144

typedef __attribute__((ext_vector_type(8))) short bf16x8;       // 8 bf16 (4 VGPR)
typedef __attribute__((ext_vector_type(4))) float f32x4;        // MFMA acc
typedef __attribute__((ext_vector_type(8))) unsigned short u16x8;

__device__ __forceinline__ unsigned short f2bf_bits(float f) {
    unsigned u = __float_as_uint(f);
    u += 0x7FFFu + ((u >> 16) & 1u);   // RNE
    return (unsigned short)(u >> 16);
}
__device__ __forceinline__ float bf2f(unsigned short h) {
    return __uint_as_float((unsigned)h << 16);
}

// ---------------------------------------------------------------------------
// Spatial mean per (b,c) from fp32 NCHW. grid = B*C blocks of 64.
// ---------------------------------------------------------------------------
__global__ __launch_bounds__(64) void mean_kernel(const float* __restrict__ in,
                                                  float* __restrict__ mean) {
    int blk = blockIdx.x;
    const float* row = in + (size_t)blk * HW;
    int t = threadIdx.x;
    float s = 0.f;
    for (int p = t; p < HW; p += 64) s += row[p];
#pragma unroll
    for (int off = 32; off > 0; off >>= 1) s += __shfl_down(s, off, 64);
    if (t == 0) mean[blk] = s * (1.0f / (float)HW);
}

// ---------------------------------------------------------------------------
// Spatial mean from bf16 NHWC [b][NP][256]. grid = B blocks of 256 (c=tid).
// ---------------------------------------------------------------------------
__global__ __launch_bounds__(256) void mean_nhwc_kernel(const __hip_bfloat16* __restrict__ a,
                                                        float* __restrict__ mean) {
    int b = blockIdx.x, c = threadIdx.x;
    const unsigned short* src = (const unsigned short*)(a + (size_t)b * NP * WIDTH) + c;
    float s = 0.f;
#pragma unroll 4
    for (int n = 0; n < HW; n++) s += bf2f(src[n * WIDTH]);
    mean[b * WIDTH + c] = s * (1.0f / (float)HW);
}

// ---------------------------------------------------------------------------
// Routing: rw[b,e] = sigmoid(mean[b,:] @ W + bias). grid = B blocks of 256.
// ---------------------------------------------------------------------------
__global__ __launch_bounds__(256) void route_kernel(const float* __restrict__ mean,
                                                    const float* __restrict__ W,
                                                    const float* __restrict__ bias,
                                                    float* __restrict__ rw, int C) {
    __shared__ float red[NE * 256];
    int b = blockIdx.x, t = threadIdx.x;
    float part[NE];
#pragma unroll
    for (int e = 0; e < NE; e++) part[e] = 0.f;
    for (int c = t; c < C; c += 256) {
        float m = mean[b * C + c];
#pragma unroll
        for (int e = 0; e < NE; e++) part[e] += m * W[c * NE + e];
    }
#pragma unroll
    for (int e = 0; e < NE; e++) red[e * 256 + t] = part[e];
    __syncthreads();
    for (int st = 128; st > 0; st >>= 1) {
        if (t < st) {
#pragma unroll
            for (int e = 0; e < NE; e++) red[e * 256 + t] += red[e * 256 + t + st];
        }
        __syncthreads();
    }
    if (t < NE) {
        float z = red[t * 256] + bias[t];
        rw[b * NE + t] = 1.0f / (1.0f + expf(-z));
    }
}

// ---------------------------------------------------------------------------
// Cast fp32 -> bf16, elementwise (n multiple of 1024). grid = n/1024.
// ---------------------------------------------------------------------------
__global__ __launch_bounds__(256) void cast_bf16_kernel(const float* __restrict__ in,
                                                        __hip_bfloat16* __restrict__ out_) {
    int i = (blockIdx.x * 256 + threadIdx.x) * 4;
    float4 v = *(const float4*)(in + i);
    unsigned short* o = (unsigned short*)out_ + i;
    o[0] = f2bf_bits(v.x); o[1] = f2bf_bits(v.y);
    o[2] = f2bf_bits(v.z); o[3] = f2bf_bits(v.w);
}

// ---------------------------------------------------------------------------
// Cast w2 fp32 [e][o][i][t9] -> bf16 [e][o][t9*256+i] (k-order permute so it
// matches the im2col buffer's k-order). grid = E*256 blocks (one per (e,o)).
// ---------------------------------------------------------------------------
__global__ __launch_bounds__(256) void cast_w2_kernel(const float* __restrict__ w2,
                                                      __hip_bfloat16* __restrict__ wb2) {
    int eo = blockIdx.x, i = threadIdx.x;
    const float* src = w2 + ((size_t)eo * 256 + i) * 9;
    unsigned short* dst = (unsigned short*)wb2 + (size_t)eo * 2304 + i;
#pragma unroll
    for (int t9 = 0; t9 < 9; t9++) dst[t9 * 256] = f2bf_bits(src[t9]);
}

// ---------------------------------------------------------------------------
// Combine expert weights (bf16 in/out): cw[b,s] = sum_e rw[b,e]*wb[e,s].
// Vectorized x8. grid = (S/2048, B).
// ---------------------------------------------------------------------------
__global__ __launch_bounds__(256) void combine_kernel(const __hip_bfloat16* __restrict__ wb,
                                                      const float* __restrict__ rw,
                                                      __hip_bfloat16* __restrict__ cw, int S) {
    int b = blockIdx.y;
    int s8 = blockIdx.x * 256 + threadIdx.x;
    const float* rwb = rw + b * NE;
    const u16x8* wv = (const u16x8*)wb;
    float acc[8];
#pragma unroll
    for (int j = 0; j < 8; j++) acc[j] = 0.f;
#pragma unroll
    for (int e = 0; e < NE; e++) {
        u16x8 v = wv[(size_t)e * (S / 8) + s8];
        float r = rwb[e];
#pragma unroll
        for (int j = 0; j < 8; j++) acc[j] += r * bf2f(v[j]);
    }
    u16x8 o;
#pragma unroll
    for (int j = 0; j < 8; j++) o[j] = f2bf_bits(acc[j]);
    ((u16x8*)cw)[(size_t)b * (S / 8) + s8] = o;
}

// ---------------------------------------------------------------------------
// Transpose x fp32 NCHW [b][1024][196] -> xb bf16 NHWC [b][224][1024]
// (pad rows zero-filled). grid = (B, NP).
// ---------------------------------------------------------------------------
__global__ __launch_bounds__(256) void transpose_x_kernel(const float* __restrict__ x,
                                                          __hip_bfloat16* __restrict__ xb) {
    int b = blockIdx.x, n = blockIdx.y, t = threadIdx.x;
    unsigned short* dst = (unsigned short*)xb + ((size_t)b * NP + n) * INP;
    if (n < HW) {
        const float* src = x + (size_t)b * INP * HW + n;
#pragma unroll
        for (int c = t; c < INP; c += 256) dst[c] = f2bf_bits(src[(size_t)c * HW]);
    } else {
        for (int c = t; c < INP; c += 256) dst[c] = 0;
    }
}

// ---------------------------------------------------------------------------
// im2col for 3x3 pad=1 from NHWC act1b [b][224][256] -> col [b][224][2304],
// k = t9*256 + i. grid = (B, NP), 256 threads (= i).
// ---------------------------------------------------------------------------
__global__ __launch_bounds__(256) void im2col_kernel(const __hip_bfloat16* __restrict__ a1,
                                                     __hip_bfloat16* __restrict__ col) {
    int b = blockIdx.x, n = blockIdx.y, i = threadIdx.x;
    unsigned short* dst = (unsigned short*)col + ((size_t)b * NP + n) * 2304 + i;
    const unsigned short* src = (const unsigned short*)a1 + (size_t)b * NP * 256 + i;
    if (n >= HW) {
#pragma unroll
        for (int t9 = 0; t9 < 9; t9++) dst[t9 * 256] = 0;
        return;
    }
    int y = n / HH, x = n % HH;
#pragma unroll
    for (int t9 = 0; t9 < 9; t9++) {
        int yy = y + t9 / 3 - 1, xx = x + t9 % 3 - 1;
        unsigned short v = 0;
        if (yy >= 0 && yy < HH && xx >= 0 && xx < HH) v = src[(size_t)(yy * HH + xx) * 256];
        dst[t9 * 256] = v;
    }
}

// ---------------------------------------------------------------------------
// Batched per-sample GEMM + BN (+residual) + ReLU, MFMA 16x16x32 bf16.
// C[b][m][n] = sum_k A[b][m][k] * Bt[b][n][k]
//   A  = combined weights, bf16 [b][M][K] row-major
//   Bt = activations,      bf16 [b][NP][K] row-major (= B transposed)
// Block 256 = 4 waves; tile M=64 (wave w: rows 16w..16w+15), N=112 (7 tiles).
// grid = (B, M/64, 2). Direct-from-global fragment loads (k-contiguous 16B),
// no LDS. Epilogue: BN scale/shift, optional fp32-NCHW residual, ReLU,
// stores to fp32 NCHW (out32) and/or bf16 NHWC (out16).
// ---------------------------------------------------------------------------
__global__ __launch_bounds__(256) void gemm_bn_kernel(
    const __hip_bfloat16* __restrict__ Bt, const __hip_bfloat16* __restrict__ A,
    const float* __restrict__ g, const float* __restrict__ be,
    const float* __restrict__ mu, const float* __restrict__ var,
    const float* __restrict__ resid, float* __restrict__ out32,
    __hip_bfloat16* __restrict__ out16, int M, int K) {
    int b = blockIdx.x, m0 = blockIdx.y * 64, n0 = blockIdx.z * 112;
    int tid = threadIdx.x, wv = tid >> 6, lane = tid & 63;
    int lo = lane & 15, g4 = lane >> 4;

    const bf16x8* Ap = (const bf16x8*)(A + ((size_t)b * M + m0 + wv * 16 + lo) * K) + g4;
    const bf16x8* Bp[7];
#pragma unroll
    for (int t = 0; t < 7; t++)
        Bp[t] = (const bf16x8*)(Bt + ((size_t)b * NP + n0 + t * 16 + lo) * K) + g4;

    f32x4 acc[7];
#pragma unroll
    for (int t = 0; t < 7; t++) acc[t] = {0.f, 0.f, 0.f, 0.f};

    int ksteps = K >> 5;
#pragma unroll 2
    for (int ks = 0; ks < ksteps; ks++) {
        bf16x8 af = Ap[ks * 4];
#pragma unroll
        for (int t = 0; t < 7; t++) {
            bf16x8 bfr = Bp[t][ks * 4];
            acc[t] = __builtin_amdgcn_mfma_f32_16x16x32_bf16(af, bfr, acc[t], 0, 0, 0);
        }
    }

    // Epilogue: C/D layout col = lane&15 (n), row = (lane>>4)*4 + r (m).
    int mbase = m0 + wv * 16 + g4 * 4;
    float sc[4], sh[4];
#pragma unroll
    for (int r = 0; r < 4; r++) {
        int mr = mbase + r;
        float iv = rsqrtf(var[mr] + EPS) * g[mr];
        sc[r] = iv;
        sh[r] = be[mr] - mu[mr] * iv;
    }
#pragma unroll
    for (int t = 0; t < 7; t++) {
        int n = n0 + t * 16 + lo;
        if (n >= HW) continue;
#pragma unroll
        for (int r = 0; r < 4; r++) {
            int mr = mbase + r;
            float v = acc[t][r] * sc[r] + sh[r];
            if (resid) v += resid[((size_t)b * M + mr) * HW + n];
            v = fmaxf(v, 0.f);
            if (out32) out32[((size_t)b * M + mr) * HW + n] = v;
            if (out16) ((unsigned short*)out16)[((size_t)b * NP + n) * M + mr] = f2bf_bits(v);
        }
    }
}

// ---------------------------------------------------------------------------
extern "C" void kernel_launch(void* const* d_in, const int* in_sizes, int n_in,
                              void* d_out, int out_size, void* d_ws, size_t ws_size,
                              hipStream_t stream) {
    const float* x    = (const float*)d_in[0];
    const float* w1   = (const float*)d_in[1];
    const float* w2   = (const float*)d_in[2];
    const float* w3   = (const float*)d_in[3];
    const float* r1_w = (const float*)d_in[4];
    const float* r1_b = (const float*)d_in[5];
    const float* r2_w = (const float*)d_in[6];
    const float* r2_b = (const float*)d_in[7];
    const float* r3_w = (const float*)d_in[8];
    const float* r3_b = (const float*)d_in[9];
    const float* bn1_g = (const float*)d_in[10];
    const float* bn1_b = (const float*)d_in[11];
    const float* bn1_m = (const float*)d_in[12];
    const float* bn1_v = (const float*)d_in[13];
    const float* bn2_g = (const float*)d_in[14];
    const float* bn2_b = (const float*)d_in[15];
    const float* bn2_m = (const float*)d_in[16];
    const float* bn2_v = (const float*)d_in[17];
    const float* bn3_g = (const float*)d_in[18];
    const float* bn3_b = (const float*)d_in[19];
    const float* bn3_m = (const float*)d_in[20];
    const float* bn3_v = (const float*)d_in[21];
    float* out = (float*)d_out;

    // Workspace layout (~96.1 MB). Region R is time-shared:
    //   [steps 2-4] xb (14.68 MB) @R+0, cw1 (16.78 MB) @R+14.68MB
    //   [steps 6-7] col2 (33.03 MB) @R+0  (xb/cw1 dead)
    //   [steps 8-9] cw3 (16.78 MB) @R+0   (col2 dead)
    char* ws = (char*)d_ws;
    size_t off = 0;
    float* meanbuf = (float*)(ws + off); off += (size_t)BB * INP * 4;
    float* rw1 = (float*)(ws + off); off += BB * NE * 4;
    float* rw2 = (float*)(ws + off); off += BB * NE * 4;
    float* rw3 = (float*)(ws + off); off += BB * NE * 4;
    __hip_bfloat16* wb1 = (__hip_bfloat16*)(ws + off); off += (size_t)S1 * NE * 2;   // 4.19 MB
    __hip_bfloat16* wb2 = (__hip_bfloat16*)(ws + off); off += (size_t)S2 * NE * 2;   // 9.44 MB
    __hip_bfloat16* wb3 = (__hip_bfloat16*)(ws + off); off += (size_t)S3 * NE * 2;   // 4.19 MB
    __hip_bfloat16* act1b = (__hip_bfloat16*)(ws + off); off += (size_t)BB * NP * WIDTH * 2;  // 3.67 MB
    __hip_bfloat16* act2b = (__hip_bfloat16*)(ws + off); off += (size_t)BB * NP * WIDTH * 2;  // 3.67 MB
    __hip_bfloat16* cw2 = (__hip_bfloat16*)(ws + off); off += (size_t)BB * S2 * 2;   // 37.75 MB
    char* region = ws + off; off += (size_t)BB * NP * 2304 * 2;                      // 33.03 MB
    __hip_bfloat16* xb   = (__hip_bfloat16*)(region);
    __hip_bfloat16* cw1  = (__hip_bfloat16*)(region + (size_t)BB * NP * INP * 2);
    __hip_bfloat16* col2 = (__hip_bfloat16*)(region);
    __hip_bfloat16* cw3  = (__hip_bfloat16*)(region);
    (void)ws_size;

    // Expert weights -> bf16 (w2 with k-permute to t9-major)
    cast_bf16_kernel<<<(S1 * NE) / 1024, 256, 0, stream>>>(w1, wb1);
    cast_w2_kernel<<<NE * 256, 256, 0, stream>>>(w2, wb2);
    cast_bf16_kernel<<<(S3 * NE) / 1024, 256, 0, stream>>>(w3, wb3);

    // x -> NHWC bf16
    transpose_x_kernel<<<dim3(BB, NP), 256, 0, stream>>>(x, xb);

    // Stage 1
    mean_kernel<<<BB * INP, 64, 0, stream>>>(x, meanbuf);
    route_kernel<<<BB, 256, 0, stream>>>(meanbuf, r1_w, r1_b, rw1, INP);
    combine_kernel<<<dim3(S1 / 2048, BB), 256, 0, stream>>>(wb1, rw1, cw1, S1);
    gemm_bn_kernel<<<dim3(BB, 4, 2), 256, 0, stream>>>(
        xb, cw1, bn1_g, bn1_b, bn1_m, bn1_v, nullptr, nullptr, act1b, WIDTH, INP);

    // Stage 2
    mean_nhwc_kernel<<<BB, 256, 0, stream>>>(act1b, meanbuf);
    route_kernel<<<BB, 256, 0, stream>>>(meanbuf, r2_w, r2_b, rw2, WIDTH);
    combine_kernel<<<dim3(S2 / 2048, BB), 256, 0, stream>>>(wb2, rw2, cw2, S2);
    im2col_kernel<<<dim3(BB, NP), 256, 0, stream>>>(act1b, col2);
    gemm_bn_kernel<<<dim3(BB, 4, 2), 256, 0, stream>>>(
        col2, cw2, bn2_g, bn2_b, bn2_m, bn2_v, nullptr, nullptr, act2b, WIDTH, 2304);

    // Stage 3
    mean_nhwc_kernel<<<BB, 256, 0, stream>>>(act2b, meanbuf);
    route_kernel<<<BB, 256, 0, stream>>>(meanbuf, r3_w, r3_b, rw3, WIDTH);
    combine_kernel<<<dim3(S3 / 2048, BB), 256, 0, stream>>>(wb3, rw3, cw3, S3);
    gemm_bn_kernel<<<dim3(BB, 16, 2), 256, 0, stream>>>(
        act2b, cw3, bn3_g, bn3_b, bn3_m, bn3_v, x, out, nullptr, OUTP, WIDTH);
}

// Round 3
// 359.441 us; speedup vs baseline: 2.3485x; 1.3472x over previous
//
#include <hip/hip_runtime.h>
#include <hip/hip_bf16.h>

#define BB 32
#define INP 1024
#define WIDTH 256
#define OUTP 1024
#define NE 8
#define HW 196
#define HH 14
#define NP 224      // padded pixel count (14 n-tiles of 16)
#define EPS 1e-5f

#define S1 (WIDTH * INP)        // 262144
#define S2 (WIDTH * WIDTH * 9)  // 589824
#define S3 (OUTP * WIDTH)       // 262144

typedef __attribute__((ext_vector_type(8))) short bf16x8;
typedef __attribute__((ext_vector_type(4))) float f32x4;
typedef __attribute__((ext_vector_type(8))) unsigned short u16x8;

__device__ __forceinline__ unsigned short f2bf_bits(float f) {
    unsigned u = __float_as_uint(f);
    u += 0x7FFFu + ((u >> 16) & 1u);   // RNE
    return (unsigned short)(u >> 16);
}
__device__ __forceinline__ float bf2f(unsigned short h) {
    return __uint_as_float((unsigned)h << 16);
}

// ---------------------------------------------------------------------------
// Fused transpose + mean of x: fp32 NCHW [b][1024][196] -> bf16 [b][224][1024]
// (pad pixels zero) and mean1[b][c]. grid (32, 64); block = (b, 16-ch chunk).
// threads 256 = (cl=tid>>4 channel, pl=tid&15 pixel) for reads; transposed
// role for writes via LDS.
// ---------------------------------------------------------------------------
__global__ __launch_bounds__(256) void transpose_mean_x(
    const float* __restrict__ x, __hip_bfloat16* __restrict__ xb,
    float* __restrict__ mean1) {
    __shared__ float lt[16][17];
    int b = blockIdx.x, c0 = blockIdx.y * 16;
    int tid = threadIdx.x, cl = tid >> 4, pl = tid & 15;
    const float* src = x + ((size_t)b * INP + c0) * HW;
    unsigned short* dst = (unsigned short*)xb + (size_t)b * NP * INP + c0;
    float msum = 0.f;
    for (int pg = 0; pg < 14; pg++) {
        int p = pg * 16 + pl;
        float v = (p < HW) ? src[(size_t)cl * HW + p] : 0.f;
        msum += v;
        lt[cl][pl] = v;
        __syncthreads();
        int pr = pg * 16 + (tid >> 4);
        dst[(size_t)pr * INP + (tid & 15)] = f2bf_bits(lt[tid & 15][tid >> 4]);
        __syncthreads();
    }
#pragma unroll
    for (int off = 8; off > 0; off >>= 1) msum += __shfl_down(msum, off, 64);
    if (pl == 0) mean1[b * INP + c0 + cl] = msum * (1.0f / (float)HW);
}

// ---------------------------------------------------------------------------
// Routing: rw[b,e] = sigmoid(mean[b,:] @ W + bias). grid = B blocks of 256.
// ---------------------------------------------------------------------------
__global__ __launch_bounds__(256) void route_kernel(const float* __restrict__ mean,
                                                    const float* __restrict__ W,
                                                    const float* __restrict__ bias,
                                                    float* __restrict__ rw, int C) {
    __shared__ float red[NE * 256];
    int b = blockIdx.x, t = threadIdx.x;
    float part[NE];
#pragma unroll
    for (int e = 0; e < NE; e++) part[e] = 0.f;
    for (int c = t; c < C; c += 256) {
        float m = mean[b * C + c];
#pragma unroll
        for (int e = 0; e < NE; e++) part[e] += m * W[c * NE + e];
    }
#pragma unroll
    for (int e = 0; e < NE; e++) red[e * 256 + t] = part[e];
    __syncthreads();
    for (int st = 128; st > 0; st >>= 1) {
        if (t < st) {
#pragma unroll
            for (int e = 0; e < NE; e++) red[e * 256 + t] += red[e * 256 + t + st];
        }
        __syncthreads();
    }
    if (t < NE) {
        float z = red[t * 256] + bias[t];
        rw[b * NE + t] = 1.0f / (1.0f + expf(-z));
    }
}

// ---------------------------------------------------------------------------
// Permute-cast w2: fp32 [e][o][i][t9] -> bf16 [e][o][t9*256+i]. grid 2048.
// ---------------------------------------------------------------------------
__global__ __launch_bounds__(256) void permute_w2_kernel(const float* __restrict__ w2,
                                                         __hip_bfloat16* __restrict__ wb2) {
    int eo = blockIdx.x, i = threadIdx.x;
    const float* src = w2 + ((size_t)eo * 256 + i) * 9;
    unsigned short* dst = (unsigned short*)wb2 + (size_t)eo * 2304 + i;
#pragma unroll
    for (int t9 = 0; t9 < 9; t9++) dst[t9 * 256] = f2bf_bits(src[t9]);
}

// ---------------------------------------------------------------------------
// Combine (fp32 experts): cw[b] = sum_e rw[b,e]*w[e]. Experts held in regs,
// loop over samples -> reads w exactly once. grid = S/2048 blocks.
// ---------------------------------------------------------------------------
__global__ __launch_bounds__(256) void combine_f32_kernel(const float* __restrict__ w,
                                                          const float* __restrict__ rw,
                                                          __hip_bfloat16* __restrict__ cw,
                                                          int S) {
    __shared__ float srw[BB * NE];
    int tid = threadIdx.x;
    srw[tid] = rw[tid];
    __syncthreads();
    size_t base = ((size_t)blockIdx.x * 256 + tid) * 8;
    float v[NE][8];
#pragma unroll
    for (int e = 0; e < NE; e++) {
        float4 a = *(const float4*)(w + (size_t)e * S + base);
        float4 c = *(const float4*)(w + (size_t)e * S + base + 4);
        v[e][0] = a.x; v[e][1] = a.y; v[e][2] = a.z; v[e][3] = a.w;
        v[e][4] = c.x; v[e][5] = c.y; v[e][6] = c.z; v[e][7] = c.w;
    }
    for (int b = 0; b < BB; b++) {
        float acc[8];
#pragma unroll
        for (int j = 0; j < 8; j++) acc[j] = 0.f;
#pragma unroll
        for (int e = 0; e < NE; e++) {
            float r = srw[b * NE + e];
#pragma unroll
            for (int j = 0; j < 8; j++) acc[j] += r * v[e][j];
        }
        u16x8 o;
#pragma unroll
        for (int j = 0; j < 8; j++) o[j] = f2bf_bits(acc[j]);
        *(u16x8*)((unsigned short*)cw + (size_t)b * S + base) = o;
    }
}

// ---------------------------------------------------------------------------
// Combine (bf16 experts, for permuted w2). grid = S2/2048 = 288 blocks.
// ---------------------------------------------------------------------------
__global__ __launch_bounds__(256) void combine_bf16_kernel(const __hip_bfloat16* __restrict__ wb,
                                                           const float* __restrict__ rw,
                                                           __hip_bfloat16* __restrict__ cw,
                                                           int S) {
    __shared__ float srw[BB * NE];
    int tid = threadIdx.x;
    srw[tid] = rw[tid];
    __syncthreads();
    size_t base8 = (size_t)blockIdx.x * 256 + tid;  // in u16x8 units
    float v[NE][8];
#pragma unroll
    for (int e = 0; e < NE; e++) {
        u16x8 raw = ((const u16x8*)wb)[(size_t)e * (S / 8) + base8];
#pragma unroll
        for (int j = 0; j < 8; j++) v[e][j] = bf2f(raw[j]);
    }
    for (int b = 0; b < BB; b++) {
        float acc[8];
#pragma unroll
        for (int j = 0; j < 8; j++) acc[j] = 0.f;
#pragma unroll
        for (int e = 0; e < NE; e++) {
            float r = srw[b * NE + e];
#pragma unroll
            for (int j = 0; j < 8; j++) acc[j] += r * v[e][j];
        }
        u16x8 o;
#pragma unroll
        for (int j = 0; j < 8; j++) o[j] = f2bf_bits(acc[j]);
        ((u16x8*)cw)[(size_t)b * (S / 8) + base8] = o;
    }
}

// ---------------------------------------------------------------------------
// Split-K GEMM partial (plain B rows): P[s][b][m][n] = A[b][m0..][k0..] * Bt.
// grid (BB, 8, S): y -> (m0 = (y>>1)*64, n0 = (y&1)*112), z = k-chunk s.
// ---------------------------------------------------------------------------
__global__ __launch_bounds__(256, 2) void gemm_plain_partial(
    const __hip_bfloat16* __restrict__ Bt, const __hip_bfloat16* __restrict__ A,
    float* __restrict__ P, int M, int K, int Kc) {
    int b = blockIdx.x, m0 = (blockIdx.y >> 1) * 64, n0 = (blockIdx.y & 1) * 112;
    int s = blockIdx.z;
    int tid = threadIdx.x, wv = tid >> 6, lane = tid & 63, lo = lane & 15, g4 = lane >> 4;
    int k0 = s * Kc;

    const bf16x8* Ap = (const bf16x8*)(A + ((size_t)b * M + m0 + wv * 16 + lo) * K + k0) + g4;
    const bf16x8* Bp[7];
#pragma unroll
    for (int t = 0; t < 7; t++)
        Bp[t] = (const bf16x8*)(Bt + ((size_t)b * NP + n0 + t * 16 + lo) * K + k0) + g4;

    f32x4 acc[7];
#pragma unroll
    for (int t = 0; t < 7; t++) acc[t] = {0.f, 0.f, 0.f, 0.f};

    int ksteps = Kc >> 5;
#pragma unroll 4
    for (int ks = 0; ks < ksteps; ks++) {
        bf16x8 af = Ap[ks * 4];
#pragma unroll
        for (int t = 0; t < 7; t++)
            acc[t] = __builtin_amdgcn_mfma_f32_16x16x32_bf16(af, Bp[t][ks * 4], acc[t], 0, 0, 0);
    }

    int mbase = m0 + wv * 16 + g4 * 4;
#pragma unroll
    for (int t = 0; t < 7; t++) {
        int n = n0 + t * 16 + lo;
#pragma unroll
        for (int r = 0; r < 4; r++)
            P[(((size_t)(s * BB + b)) * 256 + mbase + r) * NP + n] = acc[t][r];
    }
}

// ---------------------------------------------------------------------------
// Split-K GEMM partial for the 3x3 conv: B gathered from zero-haloed act1b
// [b][256 rows (16y x 16x)][256 ch]; pixel (y,x) lives at row 16(y+1)+(x+1);
// tap t9=(dy,dx) of pixel p=(y,x) is row (16y+x) + (16dy+dx) -- always
// in-bounds, halo rows are zero. grid (BB, 8, 3): z = 3-section chunk.
// ---------------------------------------------------------------------------
__global__ __launch_bounds__(256, 2) void gemm_conv3_partial(
    const __hip_bfloat16* __restrict__ act1b, const __hip_bfloat16* __restrict__ A,
    float* __restrict__ P) {
    int b = blockIdx.x, m0 = (blockIdx.y >> 1) * 64, n0 = (blockIdx.y & 1) * 112;
    int s = blockIdx.z;
    int tid = threadIdx.x, wv = tid >> 6, lane = tid & 63, lo = lane & 15, g4 = lane >> 4;

    int pb[7];
#pragma unroll
    for (int t = 0; t < 7; t++) {
        int p = n0 + t * 16 + lo;
        pb[t] = (p < HW) ? (p / HH) * 16 + (p % HH) : 0;  // sentinel ok: cols discarded
    }
    f32x4 acc[7];
#pragma unroll
    for (int t = 0; t < 7; t++) acc[t] = {0.f, 0.f, 0.f, 0.f};

    const __hip_bfloat16* Abase = A + ((size_t)b * WIDTH + m0 + wv * 16 + lo) * 2304;
    const __hip_bfloat16* Bbase = act1b + (size_t)b * 256 * 256;

#pragma unroll
    for (int sec3 = 0; sec3 < 3; sec3++) {
        int sec = s * 3 + sec3;
        int d = (sec / 3) * 16 + (sec % 3);
        const bf16x8* Ap = (const bf16x8*)(Abase + sec * 256) + g4;
        const bf16x8* Bp[7];
#pragma unroll
        for (int t = 0; t < 7; t++)
            Bp[t] = (const bf16x8*)(Bbase + (size_t)(pb[t] + d) * 256) + g4;
#pragma unroll 2
        for (int ks = 0; ks < 8; ks++) {
            bf16x8 af = Ap[ks * 4];
#pragma unroll
            for (int t = 0; t < 7; t++)
                acc[t] = __builtin_amdgcn_mfma_f32_16x16x32_bf16(af, Bp[t][ks * 4], acc[t], 0, 0, 0);
        }
    }

    int mbase = m0 + wv * 16 + g4 * 4;
#pragma unroll
    for (int t = 0; t < 7; t++) {
        int n = n0 + t * 16 + lo;
#pragma unroll
        for (int r = 0; r < 4; r++)
            P[(((size_t)(s * BB + b)) * 256 + mbase + r) * NP + n] = acc[t][r];
    }
}

// ---------------------------------------------------------------------------
// Epilogue: sum S k-chunk partials + BN + ReLU -> bf16 activation layout
// (+ per-channel spatial mean for the next routing). grid (BB, 16); block
// covers 16 channels x all 224 pixels. halo: write into 16x16 haloed layout
// (rows=256) else plain [224][256] (rows=224).
// ---------------------------------------------------------------------------
__global__ __launch_bounds__(256) void ep_kernel(
    const float* __restrict__ P, int S,
    const float* __restrict__ g, const float* __restrict__ be,
    const float* __restrict__ mu, const float* __restrict__ var,
    __hip_bfloat16* __restrict__ outb, int rows, int halo,
    float* __restrict__ meanout) {
    __shared__ float lt[16][17];
    int b = blockIdx.x, m0 = blockIdx.y * 16;
    int tid = threadIdx.x, ml = tid >> 4, nl = tid & 15;
    float iv = rsqrtf(var[m0 + ml] + EPS) * g[m0 + ml];
    float sh = be[m0 + ml] - mu[m0 + ml] * iv;
    float msum = 0.f;
    for (int ng = 0; ng < 14; ng++) {
        int n = ng * 16 + nl;
        float a = 0.f;
        for (int s = 0; s < S; s++)
            a += P[(((size_t)(s * BB + b)) * 256 + m0 + ml) * NP + n];
        a = fmaxf(a * iv + sh, 0.f);
        if (n >= HW) a = 0.f;
        msum += a;
        lt[ml][nl] = a;
        __syncthreads();
        int n2 = ng * 16 + (tid >> 4);
        if (n2 < HW) {
            int prow = halo ? ((n2 / HH) * 16 + (n2 % HH) + 17) : n2;
            ((unsigned short*)outb)[((size_t)b * rows + prow) * 256 + m0 + (tid & 15)] =
                f2bf_bits(lt[tid & 15][tid >> 4]);
        }
        __syncthreads();
    }
#pragma unroll
    for (int off = 8; off > 0; off >>= 1) msum += __shfl_down(msum, off, 64);
    if (nl == 0) meanout[b * 256 + m0 + ml] = msum * (1.0f / (float)HW);
}

// ---------------------------------------------------------------------------
// Stage-3 fused GEMM: BN + fp32 residual + ReLU -> fp32 NCHW out.
// grid (BB, 16, 2). K=256 (8 k-steps).
// ---------------------------------------------------------------------------
__global__ __launch_bounds__(256, 2) void gemm3_fused(
    const __hip_bfloat16* __restrict__ Bt, const __hip_bfloat16* __restrict__ A,
    const float* __restrict__ g, const float* __restrict__ be,
    const float* __restrict__ mu, const float* __restrict__ var,
    const float* __restrict__ resid, float* __restrict__ out32, int M, int K) {
    int b = blockIdx.x, m0 = blockIdx.y * 64, n0 = blockIdx.z * 112;
    int tid = threadIdx.x, wv = tid >> 6, lane = tid & 63, lo = lane & 15, g4 = lane >> 4;

    const bf16x8* Ap = (const bf16x8*)(A + ((size_t)b * M + m0 + wv * 16 + lo) * K) + g4;
    const bf16x8* Bp[7];
#pragma unroll
    for (int t = 0; t < 7; t++)
        Bp[t] = (const bf16x8*)(Bt + ((size_t)b * NP + n0 + t * 16 + lo) * K) + g4;

    f32x4 acc[7];
#pragma unroll
    for (int t = 0; t < 7; t++) acc[t] = {0.f, 0.f, 0.f, 0.f};

    int ksteps = K >> 5;
#pragma unroll 2
    for (int ks = 0; ks < ksteps; ks++) {
        bf16x8 af = Ap[ks * 4];
#pragma unroll
        for (int t = 0; t < 7; t++)
            acc[t] = __builtin_amdgcn_mfma_f32_16x16x32_bf16(af, Bp[t][ks * 4], acc[t], 0, 0, 0);
    }

    int mbase = m0 + wv * 16 + g4 * 4;
    float sc[4], sh[4];
#pragma unroll
    for (int r = 0; r < 4; r++) {
        int mr = mbase + r;
        float iv = rsqrtf(var[mr] + EPS) * g[mr];
        sc[r] = iv;
        sh[r] = be[mr] - mu[mr] * iv;
    }
#pragma unroll
    for (int t = 0; t < 7; t++) {
        int n = n0 + t * 16 + lo;
        if (n >= HW) continue;
#pragma unroll
        for (int r = 0; r < 4; r++) {
            int mr = mbase + r;
            float v = acc[t][r] * sc[r] + sh[r];
            v += resid[((size_t)b * M + mr) * HW + n];
            v = fmaxf(v, 0.f);
            out32[((size_t)b * M + mr) * HW + n] = v;
        }
    }
}

// ---------------------------------------------------------------------------
extern "C" void kernel_launch(void* const* d_in, const int* in_sizes, int n_in,
                              void* d_out, int out_size, void* d_ws, size_t ws_size,
                              hipStream_t stream) {
    const float* x    = (const float*)d_in[0];
    const float* w1   = (const float*)d_in[1];
    const float* w2   = (const float*)d_in[2];
    const float* w3   = (const float*)d_in[3];
    const float* r1_w = (const float*)d_in[4];
    const float* r1_b = (const float*)d_in[5];
    const float* r2_w = (const float*)d_in[6];
    const float* r2_b = (const float*)d_in[7];
    const float* r3_w = (const float*)d_in[8];
    const float* r3_b = (const float*)d_in[9];
    const float* bn1_g = (const float*)d_in[10];
    const float* bn1_b = (const float*)d_in[11];
    const float* bn1_m = (const float*)d_in[12];
    const float* bn1_v = (const float*)d_in[13];
    const float* bn2_g = (const float*)d_in[14];
    const float* bn2_b = (const float*)d_in[15];
    const float* bn2_m = (const float*)d_in[16];
    const float* bn2_v = (const float*)d_in[17];
    const float* bn3_g = (const float*)d_in[18];
    const float* bn3_b = (const float*)d_in[19];
    const float* bn3_m = (const float*)d_in[20];
    const float* bn3_v = (const float*)d_in[21];
    float* out = (float*)d_out;

    // Workspace (~94.1 MB). RegionA time-shared: xb (stages 1) then cw2
    // (stage 2) -- xb dead after gemm1, cw2 born at combine2. cwA shared by
    // cw1 (stage 1) and cw3 (stage 3).
    char* ws = (char*)d_ws;
    size_t off = 0;
    float* mean1 = (float*)(ws + off); off += (size_t)BB * INP * 4;
    float* mean2 = (float*)(ws + off); off += (size_t)BB * 256 * 4;
    float* mean3 = (float*)(ws + off); off += (size_t)BB * 256 * 4;
    float* rw1 = (float*)(ws + off); off += BB * NE * 4;
    float* rw2 = (float*)(ws + off); off += BB * NE * 4;
    float* rw3 = (float*)(ws + off); off += BB * NE * 4;
    off = (off + 255) & ~(size_t)255;
    __hip_bfloat16* wb2 = (__hip_bfloat16*)(ws + off); off += (size_t)S2 * NE * 2;       // 9.44 MB
    __hip_bfloat16* act1b = (__hip_bfloat16*)(ws + off); off += (size_t)BB * 256 * 256 * 2; // 4.19 MB
    __hip_bfloat16* act2b = (__hip_bfloat16*)(ws + off); off += (size_t)BB * NP * 256 * 2;  // 3.67 MB
    float* P = (float*)(ws + off); off += (size_t)3 * BB * 256 * NP * 4;                  // 22.02 MB
    char* regionA = ws + off; off += (size_t)BB * S2 * 2;                                 // 37.75 MB
    __hip_bfloat16* xb  = (__hip_bfloat16*)regionA;   // 14.68 MB (stage 1)
    __hip_bfloat16* cw2 = (__hip_bfloat16*)regionA;   // 37.75 MB (stage 2)
    __hip_bfloat16* cwA = (__hip_bfloat16*)(ws + off); off += (size_t)BB * S1 * 2;        // 16.78 MB
    (void)ws_size;

    // Zero-halo buffer must be cleared every call (ws is poisoned).
    hipMemsetAsync(act1b, 0, (size_t)BB * 256 * 256 * 2, stream);

    permute_w2_kernel<<<NE * 256, 256, 0, stream>>>(w2, wb2);
    transpose_mean_x<<<dim3(BB, 64), 256, 0, stream>>>(x, xb, mean1);

    // Stage 1: 1x1 conv 1024->256 (split-K S=2)
    route_kernel<<<BB, 256, 0, stream>>>(mean1, r1_w, r1_b, rw1, INP);
    combine_f32_kernel<<<S1 / 2048, 256, 0, stream>>>(w1, rw1, cwA, S1);
    gemm_plain_partial<<<dim3(BB, 8, 2), 256, 0, stream>>>(xb, cwA, P, WIDTH, INP, 512);
    ep_kernel<<<dim3(BB, 16), 256, 0, stream>>>(P, 2, bn1_g, bn1_b, bn1_m, bn1_v,
                                                act1b, 256, 1, mean2);

    // Stage 2: 3x3 conv 256->256 (split-K S=3, B gathered from haloed act1b)
    route_kernel<<<BB, 256, 0, stream>>>(mean2, r2_w, r2_b, rw2, WIDTH);
    combine_bf16_kernel<<<S2 / 2048, 256, 0, stream>>>(wb2, rw2, cw2, S2);
    gemm_conv3_partial<<<dim3(BB, 8, 3), 256, 0, stream>>>(act1b, cw2, P);
    ep_kernel<<<dim3(BB, 16), 256, 0, stream>>>(P, 3, bn2_g, bn2_b, bn2_m, bn2_v,
                                                act2b, NP, 0, mean3);

    // Stage 3: 1x1 conv 256->1024 + residual (fused epilogue)
    route_kernel<<<BB, 256, 0, stream>>>(mean3, r3_w, r3_b, rw3, WIDTH);
    combine_f32_kernel<<<S3 / 2048, 256, 0, stream>>>(w3, rw3, cwA, S3);
    gemm3_fused<<<dim3(BB, 16, 2), 256, 0, stream>>>(act2b, cwA, bn3_g, bn3_b, bn3_m,
                                                     bn3_v, x, out, OUTP, WIDTH);
}

// Round 4
// 326.892 us; speedup vs baseline: 2.5823x; 1.0996x over previous
//
#include <hip/hip_runtime.h>
#include <hip/hip_bf16.h>

#define BB 32
#define INP 1024
#define WIDTH 256
#define OUTP 1024
#define NE 8
#define HW 196
#define HH 14
#define EPS 1e-5f

#define S1 (WIDTH * INP)        // 262144
#define S2 (WIDTH * WIDTH * 9)  // 589824
#define S3 (OUTP * WIDTH)       // 262144

typedef __attribute__((ext_vector_type(8))) short bf16x8;
typedef __attribute__((ext_vector_type(4))) float f32x4;
typedef __attribute__((ext_vector_type(8))) unsigned short u16x8;

// Swizzled operand layout: tile = 16 rows x 32 k = 512 bf16 = 1 KB.
// Element (r,k) at lane*8 + (k&7), lane = (r&15) | (((k>>3)&3)<<4).
// Buffer = [.. tile-grid ..][512]; a wave's fragment load for MFMA
// 16x16x32 is exactly tile_base + lane*16B -> one coalesced 1-KB dwordx4.

__device__ __forceinline__ unsigned short f2bf_bits(float f) {
    unsigned u = __float_as_uint(f);
    u += 0x7FFFu + ((u >> 16) & 1u);   // RNE
    return (unsigned short)(u >> 16);
}
__device__ __forceinline__ float bf2f(unsigned short h) {
    return __uint_as_float((unsigned)h << 16);
}

// ---------------------------------------------------------------------------
// Fused transpose + mean of x: fp32 NCHW -> swizzled bf16 B-operand
// xb[b][nt=14][kt=32][512] + mean1[b][c]. grid (32, 8): 128-ch chunks.
// ---------------------------------------------------------------------------
__global__ __launch_bounds__(256) void transpose_mean_x(
    const float* __restrict__ x, unsigned short* __restrict__ xb,
    float* __restrict__ mean1) {
    __shared__ float lt[128][17];
    int b = blockIdx.x, c0 = blockIdx.y * 128;
    int t = threadIdx.x, cr = t >> 1, half = t & 1;
    const float* src = x + ((size_t)(b * INP + c0 + cr)) * HW;
    float msum = 0.f;
    int j = t >> 4, nl = t & 15;
    for (int pg = 0; pg < 14; pg++) {
        int p0 = pg * 16 + half * 8;
#pragma unroll
        for (int i = 0; i < 8; i++) {
            int p = p0 + i;
            float v = (p < HW) ? src[p] : 0.f;
            msum += v;
            lt[cr][half * 8 + i] = v;
        }
        __syncthreads();
        unsigned short pk[8];
#pragma unroll
        for (int i = 0; i < 8; i++) pk[i] = f2bf_bits(lt[j * 8 + i][nl]);
        size_t tile = ((size_t)b * 14 + pg) * 32 + (size_t)(blockIdx.y * 4 + (j >> 2));
        int lane = nl | ((j & 3) << 4);
        *(u16x8*)(xb + tile * 512 + lane * 8) = *(u16x8*)pk;
        __syncthreads();
    }
    float other = __shfl_xor(msum, 1, 64);
    if (half == 0) mean1[b * INP + c0 + cr] = (msum + other) * (1.0f / (float)HW);
}

// ---------------------------------------------------------------------------
// Routing: rw[b,e] = sigmoid(scale * (mean_or_sum[b,:] @ W) + bias).
// ---------------------------------------------------------------------------
__global__ __launch_bounds__(256) void route_kernel(const float* __restrict__ mean,
                                                    const float* __restrict__ W,
                                                    const float* __restrict__ bias,
                                                    float* __restrict__ rw, int C,
                                                    float scale) {
    __shared__ float red[NE * 256];
    int b = blockIdx.x, t = threadIdx.x;
    float part[NE];
#pragma unroll
    for (int e = 0; e < NE; e++) part[e] = 0.f;
    for (int c = t; c < C; c += 256) {
        float m = mean[b * C + c];
#pragma unroll
        for (int e = 0; e < NE; e++) part[e] += m * W[c * NE + e];
    }
#pragma unroll
    for (int e = 0; e < NE; e++) red[e * 256 + t] = part[e];
    __syncthreads();
    for (int st = 128; st > 0; st >>= 1) {
        if (t < st) {
#pragma unroll
            for (int e = 0; e < NE; e++) red[e * 256 + t] += red[e * 256 + t + st];
        }
        __syncthreads();
    }
    if (t < NE) {
        float z = red[t * 256] * scale + bias[t];
        rw[b * NE + t] = 1.0f / (1.0f + expf(-z));
    }
}

// ---------------------------------------------------------------------------
// Permute-cast w2: fp32 [e][o][i][t9] -> bf16 [e][o][k=t9*256+i]. grid 2048.
// ---------------------------------------------------------------------------
__global__ __launch_bounds__(256) void permute_w2_kernel(const float* __restrict__ w2,
                                                         unsigned short* __restrict__ wb2) {
    int eo = blockIdx.x, i = threadIdx.x;
    const float* src = w2 + ((size_t)eo * 256 + i) * 9;
    unsigned short* dst = wb2 + (size_t)eo * 2304 + i;
#pragma unroll
    for (int t9 = 0; t9 < 9; t9++) dst[t9 * 256] = f2bf_bits(src[t9]);
}

// ---------------------------------------------------------------------------
// Combine fp32 experts -> swizzled bf16 A-operand cw[b][Mt][Kt][512].
// Experts in regs, loop samples (reads w once). grid = S/2048.
// K is a power of two: k8bits = log2(K/8).
// ---------------------------------------------------------------------------
__global__ __launch_bounds__(256) void combine_f32_swz(
    const float* __restrict__ w, const float* __restrict__ rw,
    unsigned short* __restrict__ cw, int S, int Mt, int Kt, int k8bits) {
    __shared__ float srw[BB * NE];
    int tid = threadIdx.x;
    srw[tid] = rw[tid];
    __syncthreads();
    int idx8 = blockIdx.x * 256 + tid;
    int m = idx8 >> k8bits, k8 = idx8 & ((1 << k8bits) - 1);
    size_t srcbase = (size_t)idx8 * 8;
    float v[NE][8];
#pragma unroll
    for (int e = 0; e < NE; e++) {
        float4 a = *(const float4*)(w + (size_t)e * S + srcbase);
        float4 c = *(const float4*)(w + (size_t)e * S + srcbase + 4);
        v[e][0] = a.x; v[e][1] = a.y; v[e][2] = a.z; v[e][3] = a.w;
        v[e][4] = c.x; v[e][5] = c.y; v[e][6] = c.z; v[e][7] = c.w;
    }
    size_t dsto = ((size_t)(m >> 4) * Kt + (k8 >> 2)) * 512 + (size_t)((m & 15) | ((k8 & 3) << 4)) * 8;
    size_t bstride = (size_t)Mt * Kt * 512;
    for (int b = 0; b < BB; b++) {
        float acc[8];
#pragma unroll
        for (int jj = 0; jj < 8; jj++) acc[jj] = 0.f;
#pragma unroll
        for (int e = 0; e < NE; e++) {
            float r = srw[b * NE + e];
#pragma unroll
            for (int jj = 0; jj < 8; jj++) acc[jj] += r * v[e][jj];
        }
        u16x8 o;
#pragma unroll
        for (int jj = 0; jj < 8; jj++) o[jj] = f2bf_bits(acc[jj]);
        *(u16x8*)(cw + (size_t)b * bstride + dsto) = o;
    }
}

// ---------------------------------------------------------------------------
// Combine bf16 experts (permuted w2, K=2304) -> swizzled cw2[b][16][72][512].
// grid = 73728/256 = 288.
// ---------------------------------------------------------------------------
__global__ __launch_bounds__(256) void combine_bf16_swz(
    const unsigned short* __restrict__ wb, const float* __restrict__ rw,
    unsigned short* __restrict__ cw) {
    __shared__ float srw[BB * NE];
    int tid = threadIdx.x;
    srw[tid] = rw[tid];
    __syncthreads();
    int idx8 = blockIdx.x * 256 + tid;
    int o = idx8 / 288, k8 = idx8 - o * 288;
    float v[NE][8];
#pragma unroll
    for (int e = 0; e < NE; e++) {
        u16x8 raw = *(const u16x8*)(wb + (size_t)e * S2 + (size_t)idx8 * 8);
#pragma unroll
        for (int jj = 0; jj < 8; jj++) v[e][jj] = bf2f(raw[jj]);
    }
    size_t dsto = ((size_t)(o >> 4) * 72 + (k8 >> 2)) * 512 + (size_t)((o & 15) | ((k8 & 3) << 4)) * 8;
    for (int b = 0; b < BB; b++) {
        float acc[8];
#pragma unroll
        for (int jj = 0; jj < 8; jj++) acc[jj] = 0.f;
#pragma unroll
        for (int e = 0; e < NE; e++) {
            float r = srw[b * NE + e];
#pragma unroll
            for (int jj = 0; jj < 8; jj++) acc[jj] += r * v[e][jj];
        }
        u16x8 out;
#pragma unroll
        for (int jj = 0; jj < 8; jj++) out[jj] = f2bf_bits(acc[jj]);
        *(u16x8*)(cw + (size_t)b * 16 * 72 * 512 + dsto) = out;
    }
}

// ---------------------------------------------------------------------------
// im2col: swizzled act1[b][14][8][512] -> swizzled col[b][14][72][512]
// (k = t9*256 + i). One 16-B read (divergent) + one coalesced 16-B write
// per thread. grid = 32*14*72/4 = 8064 blocks.
// ---------------------------------------------------------------------------
__global__ __launch_bounds__(256) void im2col_swz(
    const unsigned short* __restrict__ act1, unsigned short* __restrict__ col) {
    int t = threadIdx.x, l = t & 63, lo = l & 15, g4 = l >> 4;
    int T = blockIdx.x * 4 + (t >> 6);
    int b = T / (14 * 72);
    int rem = T - b * (14 * 72);
    int nt = rem / 72;
    int kt = rem - nt * 72;
    int t9 = kt >> 3, ig = kt & 7;
    int p = nt * 16 + lo;
    u16x8 v;
#pragma unroll
    for (int jj = 0; jj < 8; jj++) v[jj] = 0;
    if (p < HW) {
        int y = p / HH, xx = p - y * HH;
        int sy = y + (t9 / 3) - 1, sx = xx + (t9 % 3) - 1;
        if (sy >= 0 && sy < HH && sx >= 0 && sx < HH) {
            int ns = sy * HH + sx;
            size_t tile = ((size_t)b * 14 + (ns >> 4)) * 8 + ig;
            v = *(const u16x8*)(act1 + tile * 512 + (size_t)((ns & 15) | (g4 << 4)) * 8);
        }
    }
    *(u16x8*)(col + ((size_t)T) * 512 + (size_t)l * 8) = v;
}

// ---------------------------------------------------------------------------
// Fused GEMM (stages 1 & 2): C = A*B^T, all operands swizzled; epilogue
// BN+ReLU -> swizzled bf16 act (Ktn=8) + per-channel spatial-sum atomics.
// grid (BB, 4, 4): wave wv handles mt = mq*4+wv (16 rows), n-quad nq
// (4 n-tiles; nq==3 has only 2 real tiles).
// ---------------------------------------------------------------------------
__global__ __launch_bounds__(256, 2) void gemm12_fused(
    const unsigned short* __restrict__ Bsw, const unsigned short* __restrict__ Asw,
    int Kt,
    const float* __restrict__ g, const float* __restrict__ be,
    const float* __restrict__ mu, const float* __restrict__ var,
    unsigned short* __restrict__ actout, float* __restrict__ msum) {
    int b = blockIdx.x, mq = blockIdx.y, nq = blockIdx.z;
    int tid = threadIdx.x, wv = tid >> 6, lane = tid & 63, lo = lane & 15, g4 = lane >> 4;
    int mt = mq * 4 + wv;
    int nt0 = nq * 4;

    const unsigned short* Ab = Asw + ((size_t)(b * 16 + mt)) * Kt * 512 + (size_t)lane * 8;
    const unsigned short* Bb[4];
#pragma unroll
    for (int tt = 0; tt < 4; tt++) {
        int nt = nt0 + tt; if (nt > 13) nt = 13;   // clamp (zeros tile), stores suppressed
        Bb[tt] = Bsw + ((size_t)(b * 14 + nt)) * Kt * 512 + (size_t)lane * 8;
    }
    f32x4 acc[4];
#pragma unroll
    for (int tt = 0; tt < 4; tt++) acc[tt] = {0.f, 0.f, 0.f, 0.f};

#pragma unroll 4
    for (int kt = 0; kt < Kt; kt++) {
        bf16x8 af = *(const bf16x8*)(Ab + (size_t)kt * 512);
#pragma unroll
        for (int tt = 0; tt < 4; tt++)
            acc[tt] = __builtin_amdgcn_mfma_f32_16x16x32_bf16(
                af, *(const bf16x8*)(Bb[tt] + (size_t)kt * 512), acc[tt], 0, 0, 0);
    }

    // Epilogue. C-tile: col n = lo, rows c = mt*16 + g4*4 + r.
    int c0 = mt * 16 + g4 * 4;
    float sc[4], sh[4];
#pragma unroll
    for (int r = 0; r < 4; r++) {
        float iv = rsqrtf(var[c0 + r] + EPS) * g[c0 + r];
        sc[r] = iv;
        sh[r] = be[c0 + r] - mu[c0 + r] * iv;
    }
    float ms[4] = {0.f, 0.f, 0.f, 0.f};
    int ktc = mt >> 1;                              // (c>>5)
    int lanehi = ((mt * 2 + (g4 >> 1)) & 3) << 4;   // ((c>>3)&3)<<4
#pragma unroll
    for (int tt = 0; tt < 4; tt++) {
        int nt = nt0 + tt;
        if (nt > 13) break;
        int n = nt * 16 + lo;
        float v[4];
#pragma unroll
        for (int r = 0; r < 4; r++) {
            float val = acc[tt][r] * sc[r] + sh[r];
            val = fmaxf(val, 0.f);
            if (n >= HW) val = 0.f;
            v[r] = val;
            ms[r] += val;
        }
        unsigned p01 = (unsigned)f2bf_bits(v[0]) | ((unsigned)f2bf_bits(v[1]) << 16);
        unsigned p23 = (unsigned)f2bf_bits(v[2]) | ((unsigned)f2bf_bits(v[3]) << 16);
        size_t off = (((size_t)(b * 14 + nt)) * 8 + ktc) * 512 + (size_t)(lo | lanehi) * 8 + (g4 & 1) * 4;
        *(uint2*)(actout + off) = make_uint2(p01, p23);
    }
#pragma unroll
    for (int r = 0; r < 4; r++) {
        float s = ms[r];
        s += __shfl_xor(s, 1, 64);
        s += __shfl_xor(s, 2, 64);
        s += __shfl_xor(s, 4, 64);
        s += __shfl_xor(s, 8, 64);
        if (lo == 0) atomicAdd(&msum[b * 256 + c0 + r], s);
    }
}

// ---------------------------------------------------------------------------
// Stage-3 fused GEMM: BN + fp32 residual + ReLU -> fp32 NCHW out.
// grid (BB, 16): mh = y>>1 (8 x 128-row blocks), nh = y&1 (7 n-tiles).
// Wave: 2 m-tiles x 7 n-tiles, K=256 (Kt=8).
// ---------------------------------------------------------------------------
__global__ __launch_bounds__(256, 2) void gemm3_fused(
    const unsigned short* __restrict__ Bsw, const unsigned short* __restrict__ Asw,
    const float* __restrict__ g, const float* __restrict__ be,
    const float* __restrict__ mu, const float* __restrict__ var,
    const float* __restrict__ resid, float* __restrict__ out) {
    int b = blockIdx.x, y = blockIdx.y, mh = y >> 1, nh = y & 1;
    int tid = threadIdx.x, wv = tid >> 6, lane = tid & 63, lo = lane & 15, g4 = lane >> 4;
    int mtb = mh * 8 + wv * 2;

    const unsigned short* Ab0 = Asw + ((size_t)(b * 64 + mtb)) * 8 * 512 + (size_t)lane * 8;
    const unsigned short* Ab1 = Ab0 + 8 * 512;
    const unsigned short* Bb[7];
#pragma unroll
    for (int tt = 0; tt < 7; tt++)
        Bb[tt] = Bsw + ((size_t)(b * 14 + nh * 7 + tt)) * 8 * 512 + (size_t)lane * 8;

    f32x4 acc0[7], acc1[7];
#pragma unroll
    for (int tt = 0; tt < 7; tt++) { acc0[tt] = {0.f, 0.f, 0.f, 0.f}; acc1[tt] = {0.f, 0.f, 0.f, 0.f}; }

#pragma unroll
    for (int kt = 0; kt < 8; kt++) {
        bf16x8 a0 = *(const bf16x8*)(Ab0 + (size_t)kt * 512);
        bf16x8 a1 = *(const bf16x8*)(Ab1 + (size_t)kt * 512);
#pragma unroll
        for (int tt = 0; tt < 7; tt++) {
            bf16x8 bf = *(const bf16x8*)(Bb[tt] + (size_t)kt * 512);
            acc0[tt] = __builtin_amdgcn_mfma_f32_16x16x32_bf16(a0, bf, acc0[tt], 0, 0, 0);
            acc1[tt] = __builtin_amdgcn_mfma_f32_16x16x32_bf16(a1, bf, acc1[tt], 0, 0, 0);
        }
    }

#pragma unroll
    for (int a = 0; a < 2; a++) {
        int m0 = (mtb + a) * 16 + g4 * 4;
        float sc[4], sh[4];
#pragma unroll
        for (int r = 0; r < 4; r++) {
            float iv = rsqrtf(var[m0 + r] + EPS) * g[m0 + r];
            sc[r] = iv;
            sh[r] = be[m0 + r] - mu[m0 + r] * iv;
        }
#pragma unroll
        for (int tt = 0; tt < 7; tt++) {
            int n = (nh * 7 + tt) * 16 + lo;
            if (n >= HW) continue;
            f32x4 av = a ? acc1[tt] : acc0[tt];
#pragma unroll
            for (int r = 0; r < 4; r++) {
                size_t oidx = ((size_t)(b * OUTP + m0 + r)) * HW + n;
                float val = av[r] * sc[r] + sh[r] + resid[oidx];
                out[oidx] = fmaxf(val, 0.f);
            }
        }
    }
}

// ---------------------------------------------------------------------------
extern "C" void kernel_launch(void* const* d_in, const int* in_sizes, int n_in,
                              void* d_out, int out_size, void* d_ws, size_t ws_size,
                              hipStream_t stream) {
    const float* x    = (const float*)d_in[0];
    const float* w1   = (const float*)d_in[1];
    const float* w2   = (const float*)d_in[2];
    const float* w3   = (const float*)d_in[3];
    const float* r1_w = (const float*)d_in[4];
    const float* r1_b = (const float*)d_in[5];
    const float* r2_w = (const float*)d_in[6];
    const float* r2_b = (const float*)d_in[7];
    const float* r3_w = (const float*)d_in[8];
    const float* r3_b = (const float*)d_in[9];
    const float* bn1_g = (const float*)d_in[10];
    const float* bn1_b = (const float*)d_in[11];
    const float* bn1_m = (const float*)d_in[12];
    const float* bn1_v = (const float*)d_in[13];
    const float* bn2_g = (const float*)d_in[14];
    const float* bn2_b = (const float*)d_in[15];
    const float* bn2_m = (const float*)d_in[16];
    const float* bn2_v = (const float*)d_in[17];
    const float* bn3_g = (const float*)d_in[18];
    const float* bn3_b = (const float*)d_in[19];
    const float* bn3_m = (const float*)d_in[20];
    const float* bn3_v = (const float*)d_in[21];
    float* out = (float*)d_out;

    // Workspace (~88 MB) with time-shared regions:
    //  cw2_region (37.75 MB): cw2 [combine2 -> gemm2]
    //  regionA (33.03 MB): epoch1 xb(14.68)+cw1(16.78) [-> gemm1];
    //                      epoch2 col [im2col -> gemm2]; epoch3 cw3.
    char* ws = (char*)d_ws;
    size_t off = 0;
    float* mean1 = (float*)(ws + off); off += (size_t)BB * INP * 4;
    float* msum2 = (float*)(ws + off); off += (size_t)BB * 256 * 4;
    float* msum3 = (float*)(ws + off); off += (size_t)BB * 256 * 4;
    float* rw1 = (float*)(ws + off); off += BB * NE * 4;
    float* rw2 = (float*)(ws + off); off += BB * NE * 4;
    float* rw3 = (float*)(ws + off); off += BB * NE * 4;
    off = (off + 255) & ~(size_t)255;
    unsigned short* wb2 = (unsigned short*)(ws + off); off += (size_t)S2 * NE * 2;          // 9.44 MB
    unsigned short* act1 = (unsigned short*)(ws + off); off += (size_t)BB * 14 * 8 * 512 * 2; // 3.67 MB
    unsigned short* act2 = (unsigned short*)(ws + off); off += (size_t)BB * 14 * 8 * 512 * 2; // 3.67 MB
    unsigned short* cw2 = (unsigned short*)(ws + off); off += (size_t)BB * 16 * 72 * 512 * 2; // 37.75 MB
    char* regionA = ws + off; off += (size_t)BB * 14 * 72 * 512 * 2;                         // 33.03 MB
    unsigned short* xb  = (unsigned short*)regionA;                       // 14.68 MB
    unsigned short* cw1 = (unsigned short*)(regionA + (size_t)BB * 14 * 32 * 512 * 2);
    unsigned short* col = (unsigned short*)regionA;
    unsigned short* cw3 = (unsigned short*)regionA;
    (void)ws_size;

    // Zero the mean-sum accumulators (atomics target; ws is poisoned).
    hipMemsetAsync(msum2, 0, (size_t)2 * BB * 256 * 4, stream);

    permute_w2_kernel<<<NE * 256, 256, 0, stream>>>(w2, wb2);
    transpose_mean_x<<<dim3(BB, 8), 256, 0, stream>>>(x, xb, mean1);

    // Stage 1: 1x1 conv 1024->256, fused BN+ReLU+mean
    route_kernel<<<BB, 256, 0, stream>>>(mean1, r1_w, r1_b, rw1, INP, 1.0f);
    combine_f32_swz<<<S1 / 2048, 256, 0, stream>>>(w1, rw1, cw1, S1, 16, 32, 7);
    gemm12_fused<<<dim3(BB, 4, 4), 256, 0, stream>>>(xb, cw1, 32,
        bn1_g, bn1_b, bn1_m, bn1_v, act1, msum2);

    // Stage 2: 3x3 conv 256->256 (swizzled im2col), fused BN+ReLU+mean
    route_kernel<<<BB, 256, 0, stream>>>(msum2, r2_w, r2_b, rw2, WIDTH, 1.0f / (float)HW);
    combine_bf16_swz<<<288, 256, 0, stream>>>(wb2, rw2, cw2);
    im2col_swz<<<BB * 14 * 72 / 4, 256, 0, stream>>>(act1, col);
    gemm12_fused<<<dim3(BB, 4, 4), 256, 0, stream>>>(col, cw2, 72,
        bn2_g, bn2_b, bn2_m, bn2_v, act2, msum3);

    // Stage 3: 1x1 conv 256->1024 + residual, fused epilogue
    route_kernel<<<BB, 256, 0, stream>>>(msum3, r3_w, r3_b, rw3, WIDTH, 1.0f / (float)HW);
    combine_f32_swz<<<S3 / 2048, 256, 0, stream>>>(w3, rw3, cw3, S3, 64, 8, 5);
    gemm3_fused<<<dim3(BB, 16), 256, 0, stream>>>(act2, cw3,
        bn3_g, bn3_b, bn3_m, bn3_v, x, out);
}

// Round 5
// 301.093 us; speedup vs baseline: 2.8036x; 1.0857x over previous
//
#include <hip/hip_runtime.h>
#include <hip/hip_bf16.h>

#define BB 32
#define INP 1024
#define WIDTH 256
#define OUTP 1024
#define NE 8
#define HW 196
#define HH 14
#define EPS 1e-5f

#define S1 (WIDTH * INP)        // 262144
#define S2 (WIDTH * WIDTH * 9)  // 589824
#define S3 (OUTP * WIDTH)       // 262144

typedef __attribute__((ext_vector_type(8))) short bf16x8;
typedef __attribute__((ext_vector_type(4))) float f32x4;
typedef __attribute__((ext_vector_type(8))) unsigned short u16x8;

// Swizzled operand layout: tile = 16 rows x 32 k = 512 bf16 = 1 KB.
// Element (r,k) at lane*8 + (k&7), lane = (r&15) | (((k>>3)&3)<<4).
// A wave's MFMA fragment load = tile_base + lane*16B (contiguous 1 KB).

__device__ __forceinline__ unsigned short f2bf_bits(float f) {
    unsigned u = __float_as_uint(f);
    u += 0x7FFFu + ((u >> 16) & 1u);   // RNE
    return (unsigned short)(u >> 16);
}
__device__ __forceinline__ float bf2f(unsigned short h) {
    return __uint_as_float((unsigned)h << 16);
}

// Async global->LDS, 16 B per lane. g = per-lane global src (16-B granule),
// l = wave-uniform LDS tile base; HW scatters at base + lane*16.
#if defined(__has_builtin)
#if __has_builtin(__builtin_amdgcn_global_load_lds)
#define HAVE_GLL 1
#endif
#endif
__device__ __forceinline__ void gl2lds(const unsigned short* g, unsigned short* l,
                                       int lane) {
#ifdef HAVE_GLL
    __builtin_amdgcn_global_load_lds(
        (const __attribute__((address_space(1))) unsigned int*)(const void*)g,
        (__attribute__((address_space(3))) unsigned int*)(void*)l, 16, 0, 0);
#else
    *(u16x8*)(l + lane * 8) = *(const u16x8*)g;
#endif
}

// ---------------------------------------------------------------------------
// Fused transpose + mean of x: fp32 NCHW -> swizzled bf16 B-operand
// xb[b][nt=14][kt=32][512] + mean1[b][c]. grid (32, 8).
// ---------------------------------------------------------------------------
__global__ __launch_bounds__(256) void transpose_mean_x(
    const float* __restrict__ x, unsigned short* __restrict__ xb,
    float* __restrict__ mean1) {
    __shared__ float lt[128][17];
    int b = blockIdx.x, c0 = blockIdx.y * 128;
    int t = threadIdx.x, cr = t >> 1, half = t & 1;
    const float* src = x + ((size_t)(b * INP + c0 + cr)) * HW;
    float msum = 0.f;
    int j = t >> 4, nl = t & 15;
    for (int pg = 0; pg < 14; pg++) {
        int p0 = pg * 16 + half * 8;
#pragma unroll
        for (int i = 0; i < 8; i++) {
            int p = p0 + i;
            float v = (p < HW) ? src[p] : 0.f;
            msum += v;
            lt[cr][half * 8 + i] = v;
        }
        __syncthreads();
        unsigned short pk[8];
#pragma unroll
        for (int i = 0; i < 8; i++) pk[i] = f2bf_bits(lt[j * 8 + i][nl]);
        size_t tile = ((size_t)b * 14 + pg) * 32 + (size_t)(blockIdx.y * 4 + (j >> 2));
        int lane = nl | ((j & 3) << 4);
        *(u16x8*)(xb + tile * 512 + lane * 8) = *(u16x8*)pk;
        __syncthreads();
    }
    float other = __shfl_xor(msum, 1, 64);
    if (half == 0) mean1[b * INP + c0 + cr] = (msum + other) * (1.0f / (float)HW);
}

// ---------------------------------------------------------------------------
// Routing: rw[b,e] = sigmoid(scale * (vec[b,:] @ W) + bias). grid = B.
// ---------------------------------------------------------------------------
__global__ __launch_bounds__(256) void route_kernel(const float* __restrict__ mean,
                                                    const float* __restrict__ W,
                                                    const float* __restrict__ bias,
                                                    float* __restrict__ rw, int C,
                                                    float scale) {
    __shared__ float red[NE * 256];
    int b = blockIdx.x, t = threadIdx.x;
    float part[NE];
#pragma unroll
    for (int e = 0; e < NE; e++) part[e] = 0.f;
    for (int c = t; c < C; c += 256) {
        float m = mean[b * C + c];
#pragma unroll
        for (int e = 0; e < NE; e++) part[e] += m * W[c * NE + e];
    }
#pragma unroll
    for (int e = 0; e < NE; e++) red[e * 256 + t] = part[e];
    __syncthreads();
    for (int st = 128; st > 0; st >>= 1) {
        if (t < st) {
#pragma unroll
            for (int e = 0; e < NE; e++) red[e * 256 + t] += red[e * 256 + t + st];
        }
        __syncthreads();
    }
    if (t < NE) {
        float z = red[t * 256] * scale + bias[t];
        rw[b * NE + t] = 1.0f / (1.0f + expf(-z));
    }
}

// ---------------------------------------------------------------------------
// Combine fp32 experts -> swizzled bf16 A-operand cw[b][Mt][Kt][512].
// grid = S/2048.
// ---------------------------------------------------------------------------
__global__ __launch_bounds__(256) void combine_f32_swz(
    const float* __restrict__ w, const float* __restrict__ rw,
    unsigned short* __restrict__ cw, int S, int Mt, int Kt, int k8bits) {
    __shared__ float srw[BB * NE];
    int tid = threadIdx.x;
    srw[tid] = rw[tid];
    __syncthreads();
    int idx8 = blockIdx.x * 256 + tid;
    int m = idx8 >> k8bits, k8 = idx8 & ((1 << k8bits) - 1);
    size_t srcbase = (size_t)idx8 * 8;
    float v[NE][8];
#pragma unroll
    for (int e = 0; e < NE; e++) {
        float4 a = *(const float4*)(w + (size_t)e * S + srcbase);
        float4 c = *(const float4*)(w + (size_t)e * S + srcbase + 4);
        v[e][0] = a.x; v[e][1] = a.y; v[e][2] = a.z; v[e][3] = a.w;
        v[e][4] = c.x; v[e][5] = c.y; v[e][6] = c.z; v[e][7] = c.w;
    }
    size_t dsto = ((size_t)(m >> 4) * Kt + (k8 >> 2)) * 512 + (size_t)((m & 15) | ((k8 & 3) << 4)) * 8;
    size_t bstride = (size_t)Mt * Kt * 512;
    for (int b = 0; b < BB; b++) {
        float acc[8];
#pragma unroll
        for (int jj = 0; jj < 8; jj++) acc[jj] = 0.f;
#pragma unroll
        for (int e = 0; e < NE; e++) {
            float r = srw[b * NE + e];
#pragma unroll
            for (int jj = 0; jj < 8; jj++) acc[jj] += r * v[e][jj];
        }
        u16x8 o;
#pragma unroll
        for (int jj = 0; jj < 8; jj++) o[jj] = f2bf_bits(acc[jj]);
        *(u16x8*)(cw + (size_t)b * bstride + dsto) = o;
    }
}

// ---------------------------------------------------------------------------
// Combine w2 directly from fp32 [e][o][i][t9] -> swizzled cw2[b][16][72][512]
// with k = t9*256 + i. Every w2 element read exactly once. grid = 288.
// ---------------------------------------------------------------------------
__global__ __launch_bounds__(256) void combine_w2_direct(
    const float* __restrict__ w2, const float* __restrict__ rw,
    unsigned short* __restrict__ cw) {
    __shared__ float srw[BB * NE];
    int tid = threadIdx.x;
    srw[tid] = rw[tid];
    __syncthreads();
    int idx8 = blockIdx.x * 256 + tid;
    int o = idx8 / 288, k8 = idx8 - o * 288;
    int t9 = k8 >> 5, i0 = (k8 & 31) * 8;
    float v[NE][8];
#pragma unroll
    for (int e = 0; e < NE; e++) {
#pragma unroll
        for (int jj = 0; jj < 8; jj++)
            v[e][jj] = w2[(((size_t)e * 256 + o) * 256 + i0 + jj) * 9 + t9];
    }
    size_t dsto = ((size_t)(o >> 4) * 72 + (k8 >> 2)) * 512 + (size_t)((o & 15) | ((k8 & 3) << 4)) * 8;
    for (int b = 0; b < BB; b++) {
        float acc[8];
#pragma unroll
        for (int jj = 0; jj < 8; jj++) acc[jj] = 0.f;
#pragma unroll
        for (int e = 0; e < NE; e++) {
            float r = srw[b * NE + e];
#pragma unroll
            for (int jj = 0; jj < 8; jj++) acc[jj] += r * v[e][jj];
        }
        u16x8 out;
#pragma unroll
        for (int jj = 0; jj < 8; jj++) out[jj] = f2bf_bits(acc[jj]);
        *(u16x8*)(cw + (size_t)b * 16 * 72 * 512 + dsto) = out;
    }
}

// ---------------------------------------------------------------------------
// im2col: swizzled act[b][14][8][512] -> swizzled col[b][14][72][512]
// (k = t9*256 + i). grid = 32*14*72/4.
// ---------------------------------------------------------------------------
__global__ __launch_bounds__(256) void im2col_swz(
    const unsigned short* __restrict__ act1, unsigned short* __restrict__ col) {
    int t = threadIdx.x, l = t & 63, lo = l & 15, g4 = l >> 4;
    int T = blockIdx.x * 4 + (t >> 6);
    int b = T / (14 * 72);
    int rem = T - b * (14 * 72);
    int nt = rem / 72;
    int kt = rem - nt * 72;
    int t9 = kt >> 3, ig = kt & 7;
    int p = nt * 16 + lo;
    u16x8 v;
#pragma unroll
    for (int jj = 0; jj < 8; jj++) v[jj] = 0;
    if (p < HW) {
        int y = p / HH, xx = p - y * HH;
        int sy = y + (t9 / 3) - 1, sx = xx + (t9 % 3) - 1;
        if (sy >= 0 && sy < HH && sx >= 0 && sx < HH) {
            int ns = sy * HH + sx;
            size_t tile = ((size_t)b * 14 + (ns >> 4)) * 8 + ig;
            v = *(const u16x8*)(act1 + tile * 512 + (size_t)((ns & 15) | (g4 << 4)) * 8);
        }
    }
    *(u16x8*)(col + ((size_t)T) * 512 + (size_t)l * 8) = v;
}

// ---------------------------------------------------------------------------
// LDS staging of one k-step: A = 8 m-tiles (128 rows), B = 7 n-tiles (112).
// ---------------------------------------------------------------------------
__device__ __forceinline__ void stage_step(
    const unsigned short* Ab, const unsigned short* Bb, int Ktot, int kt,
    unsigned short* lA, unsigned short* lB, int wv, int lane) {
#pragma unroll
    for (int j = 0; j < 2; j++) {
        int t = j * 4 + wv;
        gl2lds(Ab + ((size_t)t * Ktot + kt) * 512 + lane * 8, lA + t * 512, lane);
    }
    gl2lds(Bb + ((size_t)wv * Ktot + kt) * 512 + lane * 8, lB + wv * 512, lane);
    if (wv < 3)
        gl2lds(Bb + ((size_t)(4 + wv) * Ktot + kt) * 512 + lane * 8, lB + (4 + wv) * 512, lane);
}

__device__ __forceinline__ void compute_step(
    const unsigned short* lA, const unsigned short* lB,
    f32x4* acc0, f32x4* acc1, int wv, int lane) {
    bf16x8 a0 = *(const bf16x8*)(lA + wv * 512 + lane * 8);
    bf16x8 a1 = *(const bf16x8*)(lA + (wv + 4) * 512 + lane * 8);
#pragma unroll
    for (int t = 0; t < 7; t++) {
        bf16x8 bt = *(const bf16x8*)(lB + t * 512 + lane * 8);
        acc0[t] = __builtin_amdgcn_mfma_f32_16x16x32_bf16(a0, bt, acc0[t], 0, 0, 0);
        acc1[t] = __builtin_amdgcn_mfma_f32_16x16x32_bf16(a1, bt, acc1[t], 0, 0, 0);
    }
}

// ---------------------------------------------------------------------------
// Split-K LDS-staged GEMM (stages 1 & 2): 128x112 tile, 4 waves, dbuf x4.
// grid (BB, 4, 2): y = mh*2+nh, z = split s. Writes fp32 C-frag tiles to
// P[s][b][mt16][nt14][256].
// ---------------------------------------------------------------------------
__global__ __launch_bounds__(256) void gemm_split(
    const unsigned short* __restrict__ Bsw, const unsigned short* __restrict__ Asw,
    float* __restrict__ P, int Ktot) {
    __shared__ __align__(16) unsigned short lAb[4][8 * 512];
    __shared__ __align__(16) unsigned short lBb[4][8 * 512];
    int b = blockIdx.x, mh = blockIdx.y >> 1, nh = blockIdx.y & 1, s = blockIdx.z;
    int tid = threadIdx.x, wv = tid >> 6, lane = tid & 63;
    int ksteps = Ktot >> 1, kbase = s * ksteps;
    const unsigned short* Ab = Asw + (size_t)(b * 16 + mh * 8) * Ktot * 512;
    const unsigned short* Bb = Bsw + (size_t)(b * 14 + nh * 7) * Ktot * 512;
    f32x4 acc0[7], acc1[7];
#pragma unroll
    for (int t = 0; t < 7; t++) { acc0[t] = {0.f, 0.f, 0.f, 0.f}; acc1[t] = {0.f, 0.f, 0.f, 0.f}; }

    stage_step(Ab, Bb, Ktot, kbase + 0, lAb[0], lBb[0], wv, lane);
    stage_step(Ab, Bb, Ktot, kbase + 1, lAb[1], lBb[1], wv, lane);
    int npair = ksteps >> 1;
    for (int kp = 0; kp < npair; kp++) {
        int cb = (kp & 1) << 1, sb = 2 - cb;
        __syncthreads();
        if (kp + 1 < npair) {
            stage_step(Ab, Bb, Ktot, kbase + 2 * kp + 2, lAb[sb], lBb[sb], wv, lane);
            stage_step(Ab, Bb, Ktot, kbase + 2 * kp + 3, lAb[sb + 1], lBb[sb + 1], wv, lane);
        }
        compute_step(lAb[cb], lBb[cb], acc0, acc1, wv, lane);
        compute_step(lAb[cb + 1], lBb[cb + 1], acc0, acc1, wv, lane);
    }

#pragma unroll
    for (int a = 0; a < 2; a++) {
        int mt = mh * 8 + wv + 4 * a;
#pragma unroll
        for (int t = 0; t < 7; t++) {
            f32x4 v = a ? acc1[t] : acc0[t];
            *(f32x4*)(P + ((((size_t)s * BB + b) * 16 + mt) * 14 + nh * 7 + t) * 256 + lane * 4) = v;
        }
    }
}

// ---------------------------------------------------------------------------
// Epilogue for split-K: sum 2 partials + BN + ReLU -> swizzled bf16 act +
// per-channel spatial sums (direct store, no atomics). grid (BB, 4).
// ---------------------------------------------------------------------------
__global__ __launch_bounds__(256) void ep12(
    const float* __restrict__ P,
    const float* __restrict__ g, const float* __restrict__ be,
    const float* __restrict__ mu, const float* __restrict__ var,
    unsigned short* __restrict__ actout, float* __restrict__ msum) {
    int b = blockIdx.x;
    int tid = threadIdx.x, wv = tid >> 6, lane = tid & 63, lo = lane & 15, g4 = lane >> 4;
    int mt = blockIdx.y * 4 + wv;
    int c0 = mt * 16 + g4 * 4;
    float sc[4], sh[4];
#pragma unroll
    for (int r = 0; r < 4; r++) {
        float iv = rsqrtf(var[c0 + r] + EPS) * g[c0 + r];
        sc[r] = iv;
        sh[r] = be[c0 + r] - mu[c0 + r] * iv;
    }
    const float* P0 = P + (((size_t)b * 16 + mt) * 14) * 256 + lane * 4;
    const float* P1 = P0 + (size_t)BB * 16 * 14 * 256;
    float ms[4] = {0.f, 0.f, 0.f, 0.f};
    int ktc = mt >> 1;
    int lanehi = ((mt * 2 + (g4 >> 1)) & 3) << 4;
    for (int nt = 0; nt < 14; nt++) {
        f32x4 v0 = *(const f32x4*)(P0 + (size_t)nt * 256);
        f32x4 v1 = *(const f32x4*)(P1 + (size_t)nt * 256);
        int n = nt * 16 + lo;
        float v[4];
#pragma unroll
        for (int r = 0; r < 4; r++) {
            float val = (v0[r] + v1[r]) * sc[r] + sh[r];
            val = fmaxf(val, 0.f);
            if (n >= HW) val = 0.f;
            v[r] = val;
            ms[r] += val;
        }
        unsigned p01 = (unsigned)f2bf_bits(v[0]) | ((unsigned)f2bf_bits(v[1]) << 16);
        unsigned p23 = (unsigned)f2bf_bits(v[2]) | ((unsigned)f2bf_bits(v[3]) << 16);
        size_t off = (((size_t)(b * 14 + nt)) * 8 + ktc) * 512 + (size_t)(lo | lanehi) * 8 + (g4 & 1) * 4;
        *(uint2*)(actout + off) = make_uint2(p01, p23);
    }
#pragma unroll
    for (int r = 0; r < 4; r++) {
        float s = ms[r];
        s += __shfl_xor(s, 1, 64);
        s += __shfl_xor(s, 2, 64);
        s += __shfl_xor(s, 4, 64);
        s += __shfl_xor(s, 8, 64);
        if (lo == 0) msum[b * 256 + c0 + r] = s;
    }
}

// ---------------------------------------------------------------------------
// Stage-3 LDS-staged GEMM, fused BN + fp32 residual + ReLU -> fp32 NCHW.
// grid (BB, 16): mh = y>>1 (128-row strip of 1024), nh = y&1. K=256 (8 steps).
// ---------------------------------------------------------------------------
__global__ __launch_bounds__(256) void gemm3_fused(
    const unsigned short* __restrict__ Bsw, const unsigned short* __restrict__ Asw,
    const float* __restrict__ g, const float* __restrict__ be,
    const float* __restrict__ mu, const float* __restrict__ var,
    const float* __restrict__ resid, float* __restrict__ out) {
    __shared__ __align__(16) unsigned short lAb[4][8 * 512];
    __shared__ __align__(16) unsigned short lBb[4][8 * 512];
    int b = blockIdx.x, y = blockIdx.y, mh = y >> 1, nh = y & 1;
    int tid = threadIdx.x, wv = tid >> 6, lane = tid & 63, lo = lane & 15, g4 = lane >> 4;
    const unsigned short* Ab = Asw + (size_t)(b * 64 + mh * 8) * 8 * 512;
    const unsigned short* Bb = Bsw + (size_t)(b * 14 + nh * 7) * 8 * 512;
    f32x4 acc0[7], acc1[7];
#pragma unroll
    for (int t = 0; t < 7; t++) { acc0[t] = {0.f, 0.f, 0.f, 0.f}; acc1[t] = {0.f, 0.f, 0.f, 0.f}; }

    stage_step(Ab, Bb, 8, 0, lAb[0], lBb[0], wv, lane);
    stage_step(Ab, Bb, 8, 1, lAb[1], lBb[1], wv, lane);
#pragma unroll
    for (int kp = 0; kp < 4; kp++) {
        int cb = (kp & 1) << 1, sb = 2 - cb;
        __syncthreads();
        if (kp + 1 < 4) {
            stage_step(Ab, Bb, 8, 2 * kp + 2, lAb[sb], lBb[sb], wv, lane);
            stage_step(Ab, Bb, 8, 2 * kp + 3, lAb[sb + 1], lBb[sb + 1], wv, lane);
        }
        compute_step(lAb[cb], lBb[cb], acc0, acc1, wv, lane);
        compute_step(lAb[cb + 1], lBb[cb + 1], acc0, acc1, wv, lane);
    }

#pragma unroll
    for (int a = 0; a < 2; a++) {
        int mt = mh * 8 + wv + 4 * a;
        int c0 = mt * 16 + g4 * 4;
        float sc[4], sh[4];
#pragma unroll
        for (int r = 0; r < 4; r++) {
            float iv = rsqrtf(var[c0 + r] + EPS) * g[c0 + r];
            sc[r] = iv;
            sh[r] = be[c0 + r] - mu[c0 + r] * iv;
        }
#pragma unroll
        for (int t = 0; t < 7; t++) {
            int n = (nh * 7 + t) * 16 + lo;
            if (n >= HW) continue;
            f32x4 av = a ? acc1[t] : acc0[t];
#pragma unroll
            for (int r = 0; r < 4; r++) {
                size_t oidx = ((size_t)(b * OUTP + c0 + r)) * HW + n;
                float val = av[r] * sc[r] + sh[r] + resid[oidx];
                out[oidx] = fmaxf(val, 0.f);
            }
        }
    }
}

// ---------------------------------------------------------------------------
extern "C" void kernel_launch(void* const* d_in, const int* in_sizes, int n_in,
                              void* d_out, int out_size, void* d_ws, size_t ws_size,
                              hipStream_t stream) {
    const float* x    = (const float*)d_in[0];
    const float* w1   = (const float*)d_in[1];
    const float* w2   = (const float*)d_in[2];
    const float* w3   = (const float*)d_in[3];
    const float* r1_w = (const float*)d_in[4];
    const float* r1_b = (const float*)d_in[5];
    const float* r2_w = (const float*)d_in[6];
    const float* r2_b = (const float*)d_in[7];
    const float* r3_w = (const float*)d_in[8];
    const float* r3_b = (const float*)d_in[9];
    const float* bn1_g = (const float*)d_in[10];
    const float* bn1_b = (const float*)d_in[11];
    const float* bn1_m = (const float*)d_in[12];
    const float* bn1_v = (const float*)d_in[13];
    const float* bn2_g = (const float*)d_in[14];
    const float* bn2_b = (const float*)d_in[15];
    const float* bn2_m = (const float*)d_in[16];
    const float* bn2_v = (const float*)d_in[17];
    const float* bn3_g = (const float*)d_in[18];
    const float* bn3_b = (const float*)d_in[19];
    const float* bn3_m = (const float*)d_in[20];
    const float* bn3_v = (const float*)d_in[21];
    float* out = (float*)d_out;

    // Workspace (~89.3 MB).
    //  act (3.67 MB): stage-1 output -> im2col -> overwritten by stage-2 out.
    //  regionA (33.03 MB): epoch1 xb(14.68)+cw1(16.78); epoch2 col(33.03);
    //                      epoch3 cw3(16.78).
    char* ws = (char*)d_ws;
    size_t off = 0;
    float* mean1 = (float*)(ws + off); off += (size_t)BB * INP * 4;
    float* msum2 = (float*)(ws + off); off += (size_t)BB * 256 * 4;
    float* msum3 = (float*)(ws + off); off += (size_t)BB * 256 * 4;
    float* rw1 = (float*)(ws + off); off += BB * NE * 4;
    float* rw2 = (float*)(ws + off); off += BB * NE * 4;
    float* rw3 = (float*)(ws + off); off += BB * NE * 4;
    off = (off + 255) & ~(size_t)255;
    unsigned short* act = (unsigned short*)(ws + off); off += (size_t)BB * 14 * 8 * 512 * 2;   // 3.67 MB
    unsigned short* cw2 = (unsigned short*)(ws + off); off += (size_t)BB * 16 * 72 * 512 * 2;  // 37.75 MB
    float* P = (float*)(ws + off); off += (size_t)2 * BB * 16 * 14 * 256 * 4;                  // 14.68 MB
    char* regionA = ws + off; off += (size_t)BB * 14 * 72 * 512 * 2;                           // 33.03 MB
    unsigned short* xb  = (unsigned short*)regionA;
    unsigned short* cw1 = (unsigned short*)(regionA + (size_t)BB * 14 * 32 * 512 * 2);
    unsigned short* col = (unsigned short*)regionA;
    unsigned short* cw3 = (unsigned short*)regionA;
    (void)ws_size;

    transpose_mean_x<<<dim3(BB, 8), 256, 0, stream>>>(x, xb, mean1);

    // Stage 1: 1x1 conv 1024->256 (split-K2 LDS-staged GEMM + epilogue)
    route_kernel<<<BB, 256, 0, stream>>>(mean1, r1_w, r1_b, rw1, INP, 1.0f);
    combine_f32_swz<<<S1 / 2048, 256, 0, stream>>>(w1, rw1, cw1, S1, 16, 32, 7);
    gemm_split<<<dim3(BB, 4, 2), 256, 0, stream>>>(xb, cw1, P, 32);
    ep12<<<dim3(BB, 4), 256, 0, stream>>>(P, bn1_g, bn1_b, bn1_m, bn1_v, act, msum2);

    // Stage 2: 3x3 conv 256->256
    route_kernel<<<BB, 256, 0, stream>>>(msum2, r2_w, r2_b, rw2, WIDTH, 1.0f / (float)HW);
    combine_w2_direct<<<288, 256, 0, stream>>>(w2, rw2, cw2);
    im2col_swz<<<BB * 14 * 72 / 4, 256, 0, stream>>>(act, col);
    gemm_split<<<dim3(BB, 4, 2), 256, 0, stream>>>(col, cw2, P, 72);
    ep12<<<dim3(BB, 4), 256, 0, stream>>>(P, bn2_g, bn2_b, bn2_m, bn2_v, act, msum3);

    // Stage 3: 1x1 conv 256->1024 + residual (fused epilogue)
    route_kernel<<<BB, 256, 0, stream>>>(msum3, r3_w, r3_b, rw3, WIDTH, 1.0f / (float)HW);
    combine_f32_swz<<<S3 / 2048, 256, 0, stream>>>(w3, rw3, cw3, S3, 64, 8, 5);
    gemm3_fused<<<dim3(BB, 16), 256, 0, stream>>>(act, cw3, bn3_g, bn3_b, bn3_m, bn3_v, x, out);
}